// Round 8
// baseline (487.469 us; speedup 1.0000x reference)
//
#include <hip/hip_runtime.h>
#include <cstdint>
#include <cstddef>

typedef unsigned short u16;
typedef unsigned int u32;
typedef __attribute__((ext_vector_type(8))) short short8;
typedef __attribute__((ext_vector_type(4))) float floatx4;
typedef __attribute__((ext_vector_type(4))) u16 u16x4;
typedef __attribute__((ext_vector_type(4))) u32 u32x4;

#define DEV static __device__ __forceinline__

DEV u16 f2b(float f){ u32 u = __float_as_uint(f); u32 r = u + 0x7fffu + ((u>>16)&1u); return (u16)(r>>16); }
DEV float softplusf(float z){ return fmaxf(z,0.f) + log1pf(__expf(-fabsf(z))); }
DEV float fast_tanhf(float u){ float e = __expf(2.f*u); return 1.f - 2.f/(e+1.f); }
DEV float geluf(float x){ float u = 0.7978845608028654f*(x + 0.044715f*x*x*x); return 0.5f*x*(1.f+fast_tanhf(u)); }

DEV void async_copy16(const void* gp, void* lp){
  __builtin_amdgcn_global_load_lds((const __attribute__((address_space(1))) u32*)gp,
                                   (__attribute__((address_space(3))) u32*)lp, 16, 0, 0);
}

// LDS byte offset of a generic pointer to __shared__ (AS3 ptrs are 32-bit offsets)
DEV u32 ldsoff(const void* p){
  return (u32)(size_t)(const __attribute__((address_space(3))) char*)p;
}

// 4x ds_read_b128 with immediate offsets, OPAQUE to the compiler's waitcnt pass:
// ordering vs in-flight global_load_lds is done by OUR counted vmcnt/lgkmcnt + barriers.
DEV void ds_read128x4(u32 base, short8* dst){
  u32x4 r0, r1, r2, r3;
  asm volatile("ds_read_b128 %0, %4 offset:0\n\t"
               "ds_read_b128 %1, %4 offset:1024\n\t"
               "ds_read_b128 %2, %4 offset:2048\n\t"
               "ds_read_b128 %3, %4 offset:3072"
               : "=&v"(r0), "=&v"(r1), "=&v"(r2), "=&v"(r3)
               : "v"(base));
  union { u32x4 u; short8 s; } c0, c1, c2, c3;
  c0.u = r0; c1.u = r1; c2.u = r2; c3.u = r3;
  dst[0] = c0.s; dst[1] = c1.s; dst[2] = c2.s; dst[3] = c3.s;
}

// ---------------- fused head: all four weight casts + LN1, one launch ----------------
// blocks [0,8384): weight cast (float4 per thread).  blocks [8384,12480): LN1 rows.
__global__ __launch_bounds__(256)
void prep_ln1(const float* __restrict__ Wdbc, const float* __restrict__ Wdt,
              const float* __restrict__ Wfc, const float* __restrict__ Wproj,
              u16* __restrict__ dbc_b, u16* __restrict__ dt_b,
              u16* __restrict__ fc_b, u16* __restrict__ pj_b,
              const float* __restrict__ x, const float* __restrict__ ln1w,
              float* __restrict__ h0f, u16* __restrict__ h0b)
{
  __shared__ float red[8];
  int bx = blockIdx.x, tid = threadIdx.x;
  if (bx < 8384){
    int i = bx*256 + tid;
    const float* src; u16* dst; int j;
    if (i < 32768){
      int e = i*4, r = e >> 10;
      if (r >= 96){ u16x4 z = {0,0,0,0}; *(u16x4*)(dbc_b + e) = z; return; }
      src = Wdbc; dst = dbc_b; j = i;
    } else if (i < 49152){ src = Wdt;   dst = dt_b; j = i - 32768; }
    else if (i < 1097728){ src = Wfc;   dst = fc_b; j = i - 49152; }
    else                 { src = Wproj; dst = pj_b; j = i - 1097728; }
    float4 v = ((const float4*)src)[j];
    u16x4 o = { f2b(v.x), f2b(v.y), f2b(v.z), f2b(v.w) };
    *(u16x4*)(dst + j*4) = o;
    return;
  }
  int row = bx - 8384;
  const float4* xr = (const float4*)(x + (size_t)row*1024);
  float4 v = xr[tid];
  float s1 = v.x+v.y+v.z+v.w;
  float s2 = v.x*v.x+v.y*v.y+v.z*v.z+v.w*v.w;
  #pragma unroll
  for (int m=1;m<64;m<<=1){ s1 += __shfl_xor(s1,m); s2 += __shfl_xor(s2,m); }
  int wv = tid>>6;
  if ((tid&63)==0){ red[wv]=s1; red[4+wv]=s2; }
  __syncthreads();
  s1 = red[0]+red[1]+red[2]+red[3];
  s2 = red[4]+red[5]+red[6]+red[7];
  float mu  = s1*(1.f/1024.f);
  float var = s2*(1.f/1024.f) - mu*mu;
  float rstd = rsqrtf(var + 1e-5f);
  float4 wv4 = ((const float4*)ln1w)[tid];
  float o0 = softplusf((v.x-mu)*rstd*wv4.x);
  float o1 = softplusf((v.y-mu)*rstd*wv4.y);
  float o2 = softplusf((v.z-mu)*rstd*wv4.z);
  float o3 = softplusf((v.w-mu)*rstd*wv4.w);
  ((float4*)(h0f + (size_t)row*1024))[tid] = make_float4(o0,o1,o2,o3);
  u16x4 ob = { f2b(o0), f2b(o1), f2b(o2), f2b(o3) };
  *(u16x4*)(h0b + (size_t)row*1024 + tid*4) = ob;
}

// reduce 8 dbc split-K partials -> delta-GEMM bf16 input (cols 0..63) + f32 B/C buffer (cols 64..95)
__global__ void dbc_post(const float* __restrict__ p, u16* __restrict__ delta_in,
                         float* __restrict__ BCf){
  int e = blockIdx.x*256 + threadIdx.x;          // 524288 = 4096*128
  int t = e >> 7, c = e & 127;
  float s = 0.f;
  #pragma unroll
  for (int z=0;z<8;z++) s += p[(size_t)z*524288 + e];
  if (c < 64)      delta_in[t*64 + c] = f2b(s);
  else if (c < 96) BCf[t*32 + (c-64)] = s;
}

// ln2 + counter zero-init (counters consumed by the proj gemm's finisher epilogue)
__global__ __launch_bounds__(256)
void ln2_kernel(const float* __restrict__ x, const float* __restrict__ w,
                u16* __restrict__ outb, u32* __restrict__ cz)
{
  int row = blockIdx.x, tid = threadIdx.x;
  if (row == 0 && tid < 128) cz[tid] = 0u;       // zero cnta[64]+cntd[64] each call
  const float4* xr = (const float4*)(x + (size_t)row*1024);
  float4 v = xr[tid];
  float s1 = v.x+v.y+v.z+v.w;
  float s2 = v.x*v.x+v.y*v.y+v.z*v.z+v.w*v.w;
  #pragma unroll
  for (int m=1;m<64;m<<=1){ s1 += __shfl_xor(s1,m); s2 += __shfl_xor(s2,m); }
  __shared__ float red[8];
  int wv = tid>>6;
  if ((tid&63)==0){ red[wv]=s1; red[4+wv]=s2; }
  __syncthreads();
  s1 = red[0]+red[1]+red[2]+red[3];
  s2 = red[4]+red[5]+red[6]+red[7];
  float mu  = s1*(1.f/1024.f);
  float var = s2*(1.f/1024.f) - mu*mu;
  float rstd = rsqrtf(var + 1e-5f);
  float4 wv4 = ((const float4*)w)[tid];
  u16x4 ob = { f2b((v.x-mu)*rstd*wv4.x), f2b((v.y-mu)*rstd*wv4.y),
               f2b((v.z-mu)*rstd*wv4.z), f2b((v.w-mu)*rstd*wv4.w) };
  *(u16x4*)(outb + (size_t)row*1024 + tid*4) = ob;
}

// ---------------- MFMA GEMM (128x128, 2-barrier) — kept for the small GEMMs ----------------
template<int EPI, int SWZ>
__global__ __launch_bounds__(256)
void gemm_bt(const u16* __restrict__ A, int lda,
             const u16* __restrict__ B, int ldb, int K,
             float* __restrict__ outF, u16* __restrict__ outB, int ldo,
             const float* __restrict__ bias, size_t zstr)
{
  __shared__ u16 sA[128*32];
  __shared__ u16 sB[128*32];
  const int tid = threadIdx.x;
  int m_blk, n_blk, zb;
  if (SWZ == 0){ n_blk = blockIdx.x; m_blk = blockIdx.y; zb = blockIdx.z; }
  else if (SWZ == 1){
    int b = blockIdx.x, xcd = b & 7, local = b >> 3;
    m_blk = (xcd>>2)*16 + (local & 15);
    n_blk = (xcd&3)*8 + (local >> 4);
    zb = 0;
  } else {
    int b = blockIdx.x, xcd = b & 7, local = b >> 3;
    m_blk = (xcd>>1)*8 + (local & 7);
    n_blk = local >> 3;
    zb = xcd & 1;
  }
  const int m0 = m_blk*128, n0 = n_blk*128;
  const int kstart = zb * K;
  const int wave = tid>>6, lane = tid&63;
  const int wm = (wave>>1)*64, wn = (wave&1)*64;
  const int lr = lane&15, quad = lane>>4;

  floatx4 acc[4][4];
  #pragma unroll
  for (int i=0;i<4;i++)
    #pragma unroll
    for (int j=0;j<4;j++){ floatx4 z = {0.f,0.f,0.f,0.f}; acc[i][j]=z; }

  const int r0 = tid>>2;
  const int kc8 = (((tid&3) ^ ((tid>>3)&3)))*8;   // swizzled source k-offset (u16 units)
  const int sswz = ((lr>>1)&3);                    // reader slot xor term
  for (int k0=kstart; k0<kstart+K; k0+=32){
    __syncthreads();
    async_copy16(A + (size_t)(m0+r0)*lda    + k0+kc8, &sA[(size_t)tid*8]);
    async_copy16(A + (size_t)(m0+64+r0)*lda + k0+kc8, &sA[(size_t)(tid+256)*8]);
    async_copy16(B + (size_t)(n0+r0)*ldb    + k0+kc8, &sB[(size_t)tid*8]);
    async_copy16(B + (size_t)(n0+64+r0)*ldb + k0+kc8, &sB[(size_t)(tid+256)*8]);
    __syncthreads();
    short8 af[4], bf[4];
    #pragma unroll
    for (int i=0;i<4;i++){
      af[i] = *(const short8*)&sA[(wm+i*16+lr)*32 + (quad^sswz)*8];
      bf[i] = *(const short8*)&sB[(wn+i*16+lr)*32 + (quad^sswz)*8];
    }
    #pragma unroll
    for (int i=0;i<4;i++)
      #pragma unroll
      for (int j=0;j<4;j++)
        acc[i][j] = __builtin_amdgcn_mfma_f32_16x16x32_bf16(af[i], bf[j], acc[i][j], 0,0,0);
  }
  #pragma unroll
  for (int i=0;i<4;i++){
    #pragma unroll
    for (int j=0;j<4;j++){
      #pragma unroll
      for (int r=0;r<4;r++){
        int gr = m0 + wm + i*16 + quad*4 + r;
        int gc = n0 + wn + j*16 + lr;
        float v = acc[i][j][r];
        size_t o = (size_t)gr*ldo + gc;
        if (EPI==1)      outF[o] = softplusf(v + bias[gc]);
        else if (EPI==2) outB[o] = f2b(geluf(v));
        else             outF[zstr*zb + o] = v;
      }
    }
  }
}

// ---------------- 256x256 pipelined GEMM: asm ds_read + frag read-ahead + counted vmcnt --
// (schedule = round-4 structure, near known-best for K=1024; m248v2 848 TF ref)
// EPI 2: gelu->bf16 store.
// EPI 4: split-K with fused "last-arriver finishes" epilogue (replaces proj_reduce):
//   each tile's 4 z-blocks atomicAdd an arrive counter post-MFMA. Arrivals 0-2 store
//   their f32 partial (NORMAL stores — not the write-through atomics of r5/r6),
//   __syncthreads (drains each thread's vmcnt), tid0 __threadfence + done++.
//   Arrival 3 keeps its partial in registers, spin-waits done==3 (all 256 blocks
//   co-resident at 1/CU -> no deadlock), fences, reads 3 partials + residual out,
//   writes final out. Saves own-partial round trip (33.6MB) + the reduce launch.
// SWZ 3: FC 16x16 blocks, XCD supertile 8m x 4n.
// SWZ 4: proj — zb=xcd>>1, m=(xcd&1)*8+(local&7), n=local>>3.
template<int EPI, int SWZ>
__global__ __launch_bounds__(512, 2)
void gemm256(const u16* __restrict__ A, int lda,
             const u16* __restrict__ B, int ldb, int K,
             float* __restrict__ outF, u16* __restrict__ outB, int ldo, size_t zstr,
             float* __restrict__ pbuf, u32* __restrict__ cnta, u32* __restrict__ cntd)
{
  __shared__ u16 sA[2][4][4096];   // [buf][unit=ks*2+half][128*32]
  __shared__ u16 sB[2][4][4096];
  __shared__ u32 s_old;
  const int tid = threadIdx.x;
  int m_blk, n_blk, zb;
  if (SWZ == 3){
    int b = blockIdx.x, xcd = b & 7, local = b >> 3;
    m_blk = (xcd>>2)*8 + (local & 7);
    n_blk = (xcd&3)*4 + (local >> 3);
    zb = 0;
  } else {
    int b = blockIdx.x, xcd = b & 7, local = b >> 3;
    zb    = xcd >> 1;
    m_blk = (xcd&1)*8 + (local & 7);
    n_blk = local >> 3;
  }
  const int m0 = m_blk*256, n0 = n_blk*256;
  const int kstart = zb*K;
  const int wave = tid>>6, lane = tid&63;
  const int mq = wave>>2, nq = wave&3;
  const int lr = lane&15, quad = lane>>4;
  const int sswz = (lr>>1)&3;

  // staging source addressing (pre-swizzled chunk, rule 21: linear LDS dest)
  const int srow = tid>>2;
  const int scol = ((tid&3) ^ ((tid>>3)&3))*8;
  const u16* pa = A + (size_t)(m0 + srow)*lda + scol;
  const u16* pb = B + (size_t)(n0 + srow)*ldb + scol;
  u16* la = (u16*)sA + tid*8;
  u16* lb = (u16*)sB + tid*8;
  const size_t ah128 = (size_t)128*lda;
  const size_t bh128 = (size_t)128*ldb;

  // reader bases (u16 offsets inside one buffer)
  const int a_rd = (mq*64 + lr)*32 + (quad^sswz)*8;
  const int b_rd = ((nq&1)*64 + lr)*32 + (quad^sswz)*8;
  const int bun  = nq>>1;                       // B row-half this wave reads
  // asm ds_read byte-offset bases (unit byte off = BUF*32768 + KS*16384 + H*8192)
  const u32 a_rdB = ldsoff(sA) + (u32)(a_rd*2);
  const u32 b_rdB = ldsoff(sB) + (u32)(b_rd*2) + (u32)(bun*8192);

  floatx4 acc[2][4][4];
  #pragma unroll
  for (int h=0;h<2;h++)
    #pragma unroll
    for (int i=0;i<4;i++)
      #pragma unroll
      for (int j=0;j<4;j++){ floatx4 z={0.f,0.f,0.f,0.f}; acc[h][i][j]=z; }

  short8 af[2][4], bf[2][4];

#define STG_A(NB,KS,H,KT) async_copy16(pa + (size_t)(H)*ah128 + (size_t)((KT) + (KS)*32), \
                                       la + (NB)*16384 + ((KS)*2+(H))*4096)
#define STG_B(NB,KS,H,KT) async_copy16(pb + (size_t)(H)*bh128 + (size_t)((KT) + (KS)*32), \
                                       lb + (NB)*16384 + ((KS)*2+(H))*4096)

// MFS/MBS: frag sets consumed by this phase's MFMA; AH: acc row-half.
// PRBUF/PRKS/PRAH: unit for next phase's A pre-read (into af[MFS^1]);
// PRB: also pre-read B unit (PRKS,bun) into bf[MBS^1].
#define PH(MFS, MBS, AH, PRBUF, PRKS, PRAH, PRB, VM, LG, STMTS)               \
  {                                                                           \
    STMTS;                                                                    \
    asm volatile("s_waitcnt vmcnt(" VM ")" ::: "memory");                     \
    __builtin_amdgcn_s_barrier();                                             \
    ds_read128x4(a_rdB + (PRBUF)*32768u + (PRKS)*16384u + (PRAH)*8192u,       \
                 af[(MFS)^1]);                                                \
    if (PRB)                                                                  \
      ds_read128x4(b_rdB + (PRBUF)*32768u + (PRKS)*16384u, bf[(MBS)^1]);      \
    asm volatile("s_waitcnt lgkmcnt(" LG ")" ::: "memory");                   \
    __builtin_amdgcn_sched_barrier(0);                                        \
    __builtin_amdgcn_s_setprio(1);                                            \
    _Pragma("unroll")                                                         \
    for (int i_=0;i_<4;i_++)                                                  \
      _Pragma("unroll")                                                       \
      for (int j_=0;j_<4;j_++)                                                \
        acc[AH][i_][j_] = __builtin_amdgcn_mfma_f32_16x16x32_bf16(            \
            af[MFS][i_], bf[MBS][j_], acc[AH][i_][j_], 0,0,0);                \
    __builtin_amdgcn_s_setprio(0);                                            \
  }

  // prologue: stage tile 0 (FIFO unit order) into buf0; confirm u0-u2; pre-read ph0 frags
  STG_A(0,0,0,kstart); STG_B(0,0,0,kstart);
  STG_B(0,0,1,kstart); STG_A(0,0,1,kstart);
  STG_B(0,1,0,kstart); STG_B(0,1,1,kstart);
  STG_A(0,1,0,kstart); STG_A(0,1,1,kstart);
  asm volatile("s_waitcnt vmcnt(5)" ::: "memory");
  __builtin_amdgcn_s_barrier();
  ds_read128x4(a_rdB, af[0]);       // buf0, unit A(ks0,h0)
  ds_read128x4(b_rdB, bf[0]);       // buf0, unit B(ks0,bun)

  const int NT = K >> 6;                          // 16 for both GEMMs (even)
  for (int t=0; t<NT; t+=2){
    const int ka = kstart + (t+1)*64;                               // stage tile t+1
    const int kb = (t+2 < NT) ? (kstart + (t+2)*64) : kstart;       // stage tile t+2 / dummy
    // tile t in buf0, staging t+1 -> buf1
    PH(0,0,0, 0,0,1,0, "6","4", STG_A(1,0,0,ka); STG_B(1,0,0,ka));
    PH(1,0,1, 0,1,0,1, "5","8", STG_B(1,0,1,ka); STG_A(1,0,1,ka));
    PH(0,1,0, 0,1,1,0, "6","4", STG_B(1,1,0,ka); STG_B(1,1,1,ka));
    PH(1,1,1, 1,0,0,1, "5","8", STG_A(1,1,0,ka); STG_A(1,1,1,ka));
    // tile t+1 in buf1, staging t+2 -> buf0
    PH(0,0,0, 1,0,1,0, "6","4", STG_A(0,0,0,kb); STG_B(0,0,0,kb));
    PH(1,0,1, 1,1,0,1, "5","8", STG_B(0,0,1,kb); STG_A(0,0,1,kb));
    PH(0,1,0, 1,1,1,0, "6","4", STG_B(0,1,0,kb); STG_B(0,1,1,kb));
    PH(1,1,1, 0,0,0,1, "5","8", STG_A(0,1,0,kb); STG_A(0,1,1,kb));
  }

#undef PH
#undef STG_A
#undef STG_B

  if (EPI==2){
    #pragma unroll
    for (int h=0;h<2;h++)
      #pragma unroll
      for (int i=0;i<4;i++)
        #pragma unroll
        for (int j=0;j<4;j++)
          #pragma unroll
          for (int r=0;r<4;r++){
            int gr = m0 + h*128 + mq*64 + i*16 + quad*4 + r;
            int gc = n0 + nq*64 + j*16 + lr;
            outB[(size_t)gr*ldo + gc] = f2b(geluf(acc[h][i][j][r]));
          }
  } else {
    const int tile = m_blk*4 + n_blk;             // 16m x 4n = 64 tiles
    if (tid==0) s_old = atomicAdd(&cnta[tile], 1u);
    __syncthreads();                               // also drains dummy global_load_lds
    if (s_old < 3u){
      // not last: store partial, publish
      #pragma unroll
      for (int h=0;h<2;h++)
        #pragma unroll
        for (int i=0;i<4;i++)
          #pragma unroll
          for (int j=0;j<4;j++)
            #pragma unroll
            for (int r=0;r<4;r++){
              int gr = m0 + h*128 + mq*64 + i*16 + quad*4 + r;
              int gc = n0 + nq*64 + j*16 + lr;
              pbuf[zstr*zb + (size_t)gr*ldo + gc] = acc[h][i][j][r];
            }
      __syncthreads();                             // all threads' stores at L2 (vmcnt 0)
      if (tid==0){ __threadfence(); atomicAdd(&cntd[tile], 1u); }
    } else {
      // finisher: own partial in regs; wait for the other three, then reduce + residual
      if (tid==0){
        while (__hip_atomic_load(&cntd[tile], __ATOMIC_ACQUIRE, __HIP_MEMORY_SCOPE_AGENT) < 3u)
          __builtin_amdgcn_s_sleep(8);
      }
      __syncthreads();
      __threadfence();
      #pragma unroll
      for (int h=0;h<2;h++)
        #pragma unroll
        for (int i=0;i<4;i++)
          #pragma unroll
          for (int j=0;j<4;j++)
            #pragma unroll
            for (int r=0;r<4;r++){
              int gr = m0 + h*128 + mq*64 + i*16 + quad*4 + r;
              int gc = n0 + nq*64 + j*16 + lr;
              size_t o = (size_t)gr*ldo + gc;
              float s = acc[h][i][j][r] + outF[o];   // residual h1 already in out
              #pragma unroll
              for (int z=0;z<4;z++)
                if (z != zb) s += pbuf[zstr*z + o];
              outF[o] = s;
            }
    }
  }
}

// ---------------- chunked selective scan (32 chunks x 32 steps) ----------------
// chains: (b, d) = 4096. Lane owns (b, d, chunk), 16 n-states in registers.
// blk bits: [0:2)=d-block(4), [2:7)=chunk(32), [7:9)=b(4) -> grid 512
__global__ __launch_bounds__(256)
void scan_p1(const float* __restrict__ delta, const float* __restrict__ h0f,
             const float* __restrict__ BCf, const float* __restrict__ A_log,
             float* __restrict__ Pbuf, float* __restrict__ Sbuf)
{
  int blk = blockIdx.x;
  int d = (blk & 3)*256 + threadIdx.x;
  int c = (blk >> 2) & 31;
  int b = blk >> 7;
  float a2[16], h[16], P[16];
  #pragma unroll
  for (int n=0;n<16;n++){ a2[n] = -__expf(A_log[d*16+n]) * 1.44269504f; h[n]=0.f; P[n]=1.f; }
  int t0 = c*32;
  const float* dptr = delta + ((size_t)(b*1024 + t0))*1024 + d;
  const float* xptr = h0f   + ((size_t)(b*1024 + t0))*1024 + d;
  const float* bc   = BCf   + ((size_t)(b*1024 + t0))*32;
  #pragma unroll 4
  for (int t=0;t<32;t++){
    float dlt = dptr[t*1024];
    float xv  = xptr[t*1024];
    float dx = dlt*xv;
    #pragma unroll
    for (int n=0;n<16;n++){
      float dA = exp2f(dlt*a2[n]);
      h[n] = dA*h[n] + dx*bc[t*32+n];
      P[n] *= dA;
    }
  }
  size_t base = ((size_t)((b*32 + c)*16))*1024 + d;
  #pragma unroll
  for (int n=0;n<16;n++){ Pbuf[base + (size_t)n*1024] = P[n]; Sbuf[base + (size_t)n*1024] = h[n]; }
}

// blk bits: [0:2)=d-block(4), [2:6)=n(16), [6:8)=b(4) -> grid 256
__global__ __launch_bounds__(256)
void scan_p2(const float* __restrict__ Pbuf, const float* __restrict__ Sbuf,
             float* __restrict__ Hbuf)
{
  int blk = blockIdx.x;
  int d = (blk & 3)*256 + threadIdx.x;
  int n = (blk >> 2) & 15;
  int b = blk >> 6;
  float H = 0.f;
  for (int c=0;c<32;c++){
    size_t idx = ((size_t)((b*32 + c)*16 + n))*1024 + d;
    float P = Pbuf[idx], S = Sbuf[idx];
    Hbuf[idx] = H;
    H = P*H + S;
  }
}

// writes h1 directly into `out` (residual base; ln2 + proj finisher read it there)
__global__ __launch_bounds__(256)
void scan_p3(const float* __restrict__ delta, const float* __restrict__ h0f,
             const float* __restrict__ BCf, const float* __restrict__ A_log,
             const float* __restrict__ Hbuf, const float* __restrict__ Dp,
             float* __restrict__ outp)
{
  int blk = blockIdx.x;
  int d = (blk & 3)*256 + threadIdx.x;
  int c = (blk >> 2) & 31;
  int b = blk >> 7;
  float a2[16], h[16];
  size_t hb = ((size_t)((b*32 + c)*16))*1024 + d;
  #pragma unroll
  for (int n=0;n<16;n++){
    a2[n] = -__expf(A_log[d*16+n]) * 1.44269504f;
    h[n] = Hbuf[hb + (size_t)n*1024];
  }
  float dpv = 1.f + Dp[d];
  int t0 = c*32;
  const float* dptr = delta + ((size_t)(b*1024 + t0))*1024 + d;
  const float* xptr = h0f   + ((size_t)(b*1024 + t0))*1024 + d;
  const float* bc   = BCf   + ((size_t)(b*1024 + t0))*32;
  float* wptr = outp + ((size_t)(b*1024 + t0))*1024 + d;
  #pragma unroll 4
  for (int t=0;t<32;t++){
    float dlt = dptr[t*1024];
    float xv  = xptr[t*1024];
    float dx = dlt*xv;
    float y = 0.f;
    #pragma unroll
    for (int n=0;n<16;n++){
      float dA = exp2f(dlt*a2[n]);
      h[n] = dA*h[n] + dx*bc[t*32+n];
      y += h[n]*bc[t*32+16+n];
    }
    wptr[t*1024] = xv*dpv + y;
  }
}

// ---------------- launch ----------------
extern "C" void kernel_launch(void* const* d_in, const int* in_sizes, int n_in,
                              void* d_out, int out_size, void* d_ws, size_t ws_size,
                              hipStream_t stream)
{
  const float* x    = (const float*)d_in[0];
  const float* ln1w = (const float*)d_in[1];
  const float* ln2w = (const float*)d_in[2];
  const float* Wdbc = (const float*)d_in[3];
  const float* Wdt  = (const float*)d_in[4];
  const float* bdt  = (const float*)d_in[5];
  const float* Alog = (const float*)d_in[6];
  const float* Dp   = (const float*)d_in[7];
  const float* Wfc  = (const float*)d_in[8];
  const float* Wproj= (const float*)d_in[9];
  float* out = (float*)d_out;

  char* ws = (char*)d_ws;
  size_t off = 0;
  auto carve = [&](size_t bytes)->char*{ char* p = ws + off; off += (bytes + 255) & ~(size_t)255; return p; };
  const size_t T = 4096;                       // B*L tokens
  float* h0f   = (float*)carve(T*1024*4);
  float* dlt   = (float*)carve(T*1024*4);
  float* Pbuf  = (float*)carve((size_t)4*32*16*1024*4);   // 8MB
  float* Sbuf  = (float*)carve((size_t)4*32*16*1024*4);   // 8MB
  float* Hbuf  = (float*)carve((size_t)4*32*16*1024*4);   // 8MB
  float* pad_  = (float*)carve((size_t)4*32*16*1024*4);   // 8MB (alias space)
  float* BCf   = (float*)carve(T*32*4);
  u16*   h0b   = (u16*)  carve(T*1024*2);
  u16*   m0b   = (u16*)  carve(T*1024*2);
  u16*   g_b   = (u16*)  carve(T*4096*2);
  u16*   din_b = (u16*)  carve(T*64*2);
  u16*   Wdbc_b= (u16*)  carve((size_t)128*1024*2);
  u16*   Wdt_b = (u16*)  carve((size_t)1024*64*2);
  u16*   Wfc_b = (u16*)  carve((size_t)4096*1024*2);
  u16*   Wpj_b = (u16*)  carve((size_t)1024*4096*2);
  u32*   cnt   = (u32*)  carve(512);             // cnta[64] + cntd[64]
  // lifetime-disjoint aliases:
  float* dbc_p  = Hbuf;   // 8 x 4096x128 f32 = 16MB (Hbuf+pad_); dead before scan_p2 writes Hbuf
  // proj split-K=4 partials: 4 x 16MB = 64MB over the contiguous dead region
  // [dlt, Pbuf, Sbuf, Hbuf, pad_, BCf, h0b, m0b] (all dead after scan_p3 / FC gemm).
  float* proj_p = dlt;
  (void)pad_; (void)ws_size; (void)in_sizes; (void)n_in; (void)out_size;

  // fused head: weight casts + LN1 (independent DAG heads, one launch)
  prep_ln1<<<12480, 256, 0, stream>>>(Wdbc, Wdt, Wfc, Wproj,
                                      Wdbc_b, Wdt_b, Wfc_b, Wpj_b,
                                      x, ln1w, h0f, h0b);

  // dbc = h0 @ W_dbc^T  (N padded to 128), split-K=8 f32 partials
  gemm_bt<4,0><<<dim3(1,32,8), 256, 0, stream>>>(h0b, 1024, Wdbc_b, 1024, 128,
                                                 dbc_p, nullptr, 128, nullptr, (size_t)T*128);
  // reduce partials -> delta-input bf16 + B/C f32
  dbc_post<<<2048, 256, 0, stream>>>(dbc_p, din_b, BCf);

  // delta = softplus(din @ W_dt^T + b_dt), f32 out
  gemm_bt<1,0><<<dim3(8,32), 256, 0, stream>>>(din_b, 64, Wdt_b, 64, 64,
                                               dlt, nullptr, 1024, bdt, 0);

  // selective scan -> out = h1 = h0*(1+Dp) + y  (residual base; ln2 reads it)
  scan_p1<<<512, 256, 0, stream>>>(dlt, h0f, BCf, Alog, Pbuf, Sbuf);
  scan_p2<<<256, 256, 0, stream>>>(Pbuf, Sbuf, Hbuf);
  scan_p3<<<512, 256, 0, stream>>>(dlt, h0f, BCf, Alog, Hbuf, Dp, out);

  // m0 = LN2(h1) (bf16) — reads h1 from out; also zeroes proj finisher counters
  ln2_kernel<<<4096, 256, 0, stream>>>(out, ln2w, m0b, cnt);

  // g = gelu(m0 @ W_fc^T) (bf16) — 256^2 pipelined (asm ds_read), XCD supertiled
  gemm256<2,3><<<256, 512, 0, stream>>>(m0b, 1024, Wfc_b, 1024, 1024,
                                        nullptr, g_b, 4096, 0, nullptr, nullptr, nullptr);

  // out += g @ W_proj^T: split-K=4 with fused last-arriver reduction (no proj_reduce)
  gemm256<4,4><<<256, 512, 0, stream>>>(g_b, 4096, Wpj_b, 4096, 1024,
                                        out, nullptr, 1024, (size_t)T*1024,
                                        proj_p, cnt, cnt + 64);
}

// Round 10
// 325.153 us; speedup vs baseline: 1.4992x; 1.4992x over previous
//
#include <hip/hip_runtime.h>
#include <cstdint>
#include <cstddef>

typedef unsigned short u16;
typedef unsigned int u32;
typedef __attribute__((ext_vector_type(8))) short short8;
typedef __attribute__((ext_vector_type(4))) float floatx4;
typedef __attribute__((ext_vector_type(4))) u16 u16x4;
typedef __attribute__((ext_vector_type(4))) u32 u32x4;

#define DEV static __device__ __forceinline__

DEV u16 f2b(float f){ u32 u = __float_as_uint(f); u32 r = u + 0x7fffu + ((u>>16)&1u); return (u16)(r>>16); }
DEV float softplusf(float z){ return fmaxf(z,0.f) + log1pf(__expf(-fabsf(z))); }
DEV float fast_tanhf(float u){ float e = __expf(2.f*u); return 1.f - 2.f/(e+1.f); }
DEV float geluf(float x){ float u = 0.7978845608028654f*(x + 0.044715f*x*x*x); return 0.5f*x*(1.f+fast_tanhf(u)); }

DEV void async_copy16(const void* gp, void* lp){
  __builtin_amdgcn_global_load_lds((const __attribute__((address_space(1))) u32*)gp,
                                   (__attribute__((address_space(3))) u32*)lp, 16, 0, 0);
}

// LDS byte offset of a generic pointer to __shared__ (AS3 ptrs are 32-bit offsets)
DEV u32 ldsoff(const void* p){
  return (u32)(size_t)(const __attribute__((address_space(3))) char*)p;
}

// 4x ds_read_b128 with immediate offsets, OPAQUE to the compiler's waitcnt pass:
// ordering vs in-flight global_load_lds is done by OUR counted vmcnt/lgkmcnt + barriers.
DEV void ds_read128x4(u32 base, short8* dst){
  u32x4 r0, r1, r2, r3;
  asm volatile("ds_read_b128 %0, %4 offset:0\n\t"
               "ds_read_b128 %1, %4 offset:1024\n\t"
               "ds_read_b128 %2, %4 offset:2048\n\t"
               "ds_read_b128 %3, %4 offset:3072"
               : "=&v"(r0), "=&v"(r1), "=&v"(r2), "=&v"(r3)
               : "v"(base));
  union { u32x4 u; short8 s; } c0, c1, c2, c3;
  c0.u = r0; c1.u = r1; c2.u = r2; c3.u = r3;
  dst[0] = c0.s; dst[1] = c1.s; dst[2] = c2.s; dst[3] = c3.s;
}

// ---------------- fused head: all four weight casts + LN1, one launch ----------------
// blocks [0,8384): weight cast (float4 per thread).  blocks [8384,12480): LN1 rows.
__global__ __launch_bounds__(256)
void prep_ln1(const float* __restrict__ Wdbc, const float* __restrict__ Wdt,
              const float* __restrict__ Wfc, const float* __restrict__ Wproj,
              u16* __restrict__ dbc_b, u16* __restrict__ dt_b,
              u16* __restrict__ fc_b, u16* __restrict__ pj_b,
              const float* __restrict__ x, const float* __restrict__ ln1w,
              float* __restrict__ h0f, u16* __restrict__ h0b)
{
  __shared__ float red[8];
  int bx = blockIdx.x, tid = threadIdx.x;
  if (bx < 8384){
    int i = bx*256 + tid;
    const float* src; u16* dst; int j;
    if (i < 32768){
      int e = i*4, r = e >> 10;
      if (r >= 96){ u16x4 z = {0,0,0,0}; *(u16x4*)(dbc_b + e) = z; return; }
      src = Wdbc; dst = dbc_b; j = i;
    } else if (i < 49152){ src = Wdt;   dst = dt_b; j = i - 32768; }
    else if (i < 1097728){ src = Wfc;   dst = fc_b; j = i - 49152; }
    else                 { src = Wproj; dst = pj_b; j = i - 1097728; }
    float4 v = ((const float4*)src)[j];
    u16x4 o = { f2b(v.x), f2b(v.y), f2b(v.z), f2b(v.w) };
    *(u16x4*)(dst + j*4) = o;
    return;
  }
  int row = bx - 8384;
  const float4* xr = (const float4*)(x + (size_t)row*1024);
  float4 v = xr[tid];
  float s1 = v.x+v.y+v.z+v.w;
  float s2 = v.x*v.x+v.y*v.y+v.z*v.z+v.w*v.w;
  #pragma unroll
  for (int m=1;m<64;m<<=1){ s1 += __shfl_xor(s1,m); s2 += __shfl_xor(s2,m); }
  int wv = tid>>6;
  if ((tid&63)==0){ red[wv]=s1; red[4+wv]=s2; }
  __syncthreads();
  s1 = red[0]+red[1]+red[2]+red[3];
  s2 = red[4]+red[5]+red[6]+red[7];
  float mu  = s1*(1.f/1024.f);
  float var = s2*(1.f/1024.f) - mu*mu;
  float rstd = rsqrtf(var + 1e-5f);
  float4 wv4 = ((const float4*)ln1w)[tid];
  float o0 = softplusf((v.x-mu)*rstd*wv4.x);
  float o1 = softplusf((v.y-mu)*rstd*wv4.y);
  float o2 = softplusf((v.z-mu)*rstd*wv4.z);
  float o3 = softplusf((v.w-mu)*rstd*wv4.w);
  ((float4*)(h0f + (size_t)row*1024))[tid] = make_float4(o0,o1,o2,o3);
  u16x4 ob = { f2b(o0), f2b(o1), f2b(o2), f2b(o3) };
  *(u16x4*)(h0b + (size_t)row*1024 + tid*4) = ob;
}

// reduce 8 dbc split-K partials -> delta-GEMM bf16 input (cols 0..63) + f32 B/C buffer (cols 64..95)
__global__ void dbc_post(const float* __restrict__ p, u16* __restrict__ delta_in,
                         float* __restrict__ BCf){
  int e = blockIdx.x*256 + threadIdx.x;          // 524288 = 4096*128
  int t = e >> 7, c = e & 127;
  float s = 0.f;
  #pragma unroll
  for (int z=0;z<8;z++) s += p[(size_t)z*524288 + e];
  if (c < 64)      delta_in[t*64 + c] = f2b(s);
  else if (c < 96) BCf[t*32 + (c-64)] = s;
}

// out = p0+p1+p2+p3 + out  (proj split-K=4 reduce; out holds the residual h1)
__global__ void proj_reduce(const float* __restrict__ p, float* __restrict__ out){
  int i = blockIdx.x*256 + threadIdx.x;          // over 1M float4
  float4 a = ((const float4*)p)[i];
  float4 b = ((const float4*)(p + (size_t) 4194304))[i];
  float4 c = ((const float4*)(p + (size_t) 8388608))[i];
  float4 d = ((const float4*)(p + (size_t)12582912))[i];
  float4 r = ((float4*)out)[i];
  float4 o = make_float4(a.x+b.x+c.x+d.x+r.x, a.y+b.y+c.y+d.y+r.y,
                         a.z+b.z+c.z+d.z+r.z, a.w+b.w+c.w+d.w+r.w);
  ((float4*)out)[i] = o;
}

__global__ __launch_bounds__(256)
void ln2_kernel(const float* __restrict__ x, const float* __restrict__ w,
                u16* __restrict__ outb)
{
  int row = blockIdx.x, tid = threadIdx.x;
  const float4* xr = (const float4*)(x + (size_t)row*1024);
  float4 v = xr[tid];
  float s1 = v.x+v.y+v.z+v.w;
  float s2 = v.x*v.x+v.y*v.y+v.z*v.z+v.w*v.w;
  #pragma unroll
  for (int m=1;m<64;m<<=1){ s1 += __shfl_xor(s1,m); s2 += __shfl_xor(s2,m); }
  __shared__ float red[8];
  int wv = tid>>6;
  if ((tid&63)==0){ red[wv]=s1; red[4+wv]=s2; }
  __syncthreads();
  s1 = red[0]+red[1]+red[2]+red[3];
  s2 = red[4]+red[5]+red[6]+red[7];
  float mu  = s1*(1.f/1024.f);
  float var = s2*(1.f/1024.f) - mu*mu;
  float rstd = rsqrtf(var + 1e-5f);
  float4 wv4 = ((const float4*)w)[tid];
  u16x4 ob = { f2b((v.x-mu)*rstd*wv4.x), f2b((v.y-mu)*rstd*wv4.y),
               f2b((v.z-mu)*rstd*wv4.z), f2b((v.w-mu)*rstd*wv4.w) };
  *(u16x4*)(outb + (size_t)row*1024 + tid*4) = ob;
}

// ---------------- MFMA GEMM (128x128, 2-barrier) — kept for the small GEMMs ----------------
template<int EPI, int SWZ>
__global__ __launch_bounds__(256)
void gemm_bt(const u16* __restrict__ A, int lda,
             const u16* __restrict__ B, int ldb, int K,
             float* __restrict__ outF, u16* __restrict__ outB, int ldo,
             const float* __restrict__ bias, size_t zstr)
{
  __shared__ u16 sA[128*32];
  __shared__ u16 sB[128*32];
  const int tid = threadIdx.x;
  int m_blk, n_blk, zb;
  if (SWZ == 0){ n_blk = blockIdx.x; m_blk = blockIdx.y; zb = blockIdx.z; }
  else if (SWZ == 1){
    int b = blockIdx.x, xcd = b & 7, local = b >> 3;
    m_blk = (xcd>>2)*16 + (local & 15);
    n_blk = (xcd&3)*8 + (local >> 4);
    zb = 0;
  } else {
    int b = blockIdx.x, xcd = b & 7, local = b >> 3;
    m_blk = (xcd>>1)*8 + (local & 7);
    n_blk = local >> 3;
    zb = xcd & 1;
  }
  const int m0 = m_blk*128, n0 = n_blk*128;
  const int kstart = zb * K;
  const int wave = tid>>6, lane = tid&63;
  const int wm = (wave>>1)*64, wn = (wave&1)*64;
  const int lr = lane&15, quad = lane>>4;

  floatx4 acc[4][4];
  #pragma unroll
  for (int i=0;i<4;i++)
    #pragma unroll
    for (int j=0;j<4;j++){ floatx4 z = {0.f,0.f,0.f,0.f}; acc[i][j]=z; }

  const int r0 = tid>>2;
  const int kc8 = (((tid&3) ^ ((tid>>3)&3)))*8;   // swizzled source k-offset (u16 units)
  const int sswz = ((lr>>1)&3);                    // reader slot xor term
  for (int k0=kstart; k0<kstart+K; k0+=32){
    __syncthreads();
    async_copy16(A + (size_t)(m0+r0)*lda    + k0+kc8, &sA[(size_t)tid*8]);
    async_copy16(A + (size_t)(m0+64+r0)*lda + k0+kc8, &sA[(size_t)(tid+256)*8]);
    async_copy16(B + (size_t)(n0+r0)*ldb    + k0+kc8, &sB[(size_t)tid*8]);
    async_copy16(B + (size_t)(n0+64+r0)*ldb + k0+kc8, &sB[(size_t)(tid+256)*8]);
    __syncthreads();
    short8 af[4], bf[4];
    #pragma unroll
    for (int i=0;i<4;i++){
      af[i] = *(const short8*)&sA[(wm+i*16+lr)*32 + (quad^sswz)*8];
      bf[i] = *(const short8*)&sB[(wn+i*16+lr)*32 + (quad^sswz)*8];
    }
    #pragma unroll
    for (int i=0;i<4;i++)
      #pragma unroll
      for (int j=0;j<4;j++)
        acc[i][j] = __builtin_amdgcn_mfma_f32_16x16x32_bf16(af[i], bf[j], acc[i][j], 0,0,0);
  }
  #pragma unroll
  for (int i=0;i<4;i++){
    #pragma unroll
    for (int j=0;j<4;j++){
      #pragma unroll
      for (int r=0;r<4;r++){
        int gr = m0 + wm + i*16 + quad*4 + r;
        int gc = n0 + wn + j*16 + lr;
        float v = acc[i][j][r];
        size_t o = (size_t)gr*ldo + gc;
        if (EPI==1)      outF[o] = softplusf(v + bias[gc]);
        else if (EPI==2) outB[o] = f2b(geluf(v));
        else             outF[zstr*zb + o] = v;
      }
    }
  }
}

// ---------------- 256x256 pipelined GEMM: asm ds_read + frag read-ahead + counted vmcnt --
// (round-7 proven structure; 45us / MfmaUtil 29% on FC and proj at K=1024)
// EPI 2: gelu->bf16 store.  EPI 4: f32 split-K partial store at zstr*zb. NO atomics and
// NO intra-kernel cross-block reduction — both failed on gfx950: f32 global atomics
// write through to HBM (r5/r6: WRITE=64MB); intra-kernel hand-off is cross-XCD under
// any useful swizzle -> per-tile L2 fence writeback/invalidate (r8: 234us, FETCH 59MB).
// Inter-tile reduction belongs in a stream-ordered launch (proj_reduce).
// SWZ 3: FC 16x16 blocks, XCD supertile 8m x 4n.
// SWZ 4: proj — zb=xcd>>1, m=(xcd&1)*8+(local&7), n=local>>3.
template<int EPI, int SWZ>
__global__ __launch_bounds__(512, 2)
void gemm256(const u16* __restrict__ A, int lda,
             const u16* __restrict__ B, int ldb, int K,
             float* __restrict__ outF, u16* __restrict__ outB, int ldo, size_t zstr)
{
  __shared__ u16 sA[2][4][4096];   // [buf][unit=ks*2+half][128*32]
  __shared__ u16 sB[2][4][4096];
  const int tid = threadIdx.x;
  int m_blk, n_blk, zb;
  if (SWZ == 3){
    int b = blockIdx.x, xcd = b & 7, local = b >> 3;
    m_blk = (xcd>>2)*8 + (local & 7);
    n_blk = (xcd&3)*4 + (local >> 3);
    zb = 0;
  } else {
    int b = blockIdx.x, xcd = b & 7, local = b >> 3;
    zb    = xcd >> 1;
    m_blk = (xcd&1)*8 + (local & 7);
    n_blk = local >> 3;
  }
  const int m0 = m_blk*256, n0 = n_blk*256;
  const int kstart = zb*K;
  const int wave = tid>>6, lane = tid&63;
  const int mq = wave>>2, nq = wave&3;
  const int lr = lane&15, quad = lane>>4;
  const int sswz = (lr>>1)&3;

  // staging source addressing (pre-swizzled chunk, rule 21: linear LDS dest)
  const int srow = tid>>2;
  const int scol = ((tid&3) ^ ((tid>>3)&3))*8;
  const u16* pa = A + (size_t)(m0 + srow)*lda + scol;
  const u16* pb = B + (size_t)(n0 + srow)*ldb + scol;
  u16* la = (u16*)sA + tid*8;
  u16* lb = (u16*)sB + tid*8;
  const size_t ah128 = (size_t)128*lda;
  const size_t bh128 = (size_t)128*ldb;

  // reader bases (u16 offsets inside one buffer)
  const int a_rd = (mq*64 + lr)*32 + (quad^sswz)*8;
  const int b_rd = ((nq&1)*64 + lr)*32 + (quad^sswz)*8;
  const int bun  = nq>>1;                       // B row-half this wave reads
  // asm ds_read byte-offset bases (unit byte off = BUF*32768 + KS*16384 + H*8192)
  const u32 a_rdB = ldsoff(sA) + (u32)(a_rd*2);
  const u32 b_rdB = ldsoff(sB) + (u32)(b_rd*2) + (u32)(bun*8192);

  floatx4 acc[2][4][4];
  #pragma unroll
  for (int h=0;h<2;h++)
    #pragma unroll
    for (int i=0;i<4;i++)
      #pragma unroll
      for (int j=0;j<4;j++){ floatx4 z={0.f,0.f,0.f,0.f}; acc[h][i][j]=z; }

  short8 af[2][4], bf[2][4];

#define STG_A(NB,KS,H,KT) async_copy16(pa + (size_t)(H)*ah128 + (size_t)((KT) + (KS)*32), \
                                       la + (NB)*16384 + ((KS)*2+(H))*4096)
#define STG_B(NB,KS,H,KT) async_copy16(pb + (size_t)(H)*bh128 + (size_t)((KT) + (KS)*32), \
                                       lb + (NB)*16384 + ((KS)*2+(H))*4096)

// MFS/MBS: frag sets consumed by this phase's MFMA; AH: acc row-half.
// PRBUF/PRKS/PRAH: unit for next phase's A pre-read (into af[MFS^1]);
// PRB: also pre-read B unit (PRKS,bun) into bf[MBS^1].
#define PH(MFS, MBS, AH, PRBUF, PRKS, PRAH, PRB, VM, LG, STMTS)               \
  {                                                                           \
    STMTS;                                                                    \
    asm volatile("s_waitcnt vmcnt(" VM ")" ::: "memory");                     \
    __builtin_amdgcn_s_barrier();                                             \
    ds_read128x4(a_rdB + (PRBUF)*32768u + (PRKS)*16384u + (PRAH)*8192u,       \
                 af[(MFS)^1]);                                                \
    if (PRB)                                                                  \
      ds_read128x4(b_rdB + (PRBUF)*32768u + (PRKS)*16384u, bf[(MBS)^1]);      \
    asm volatile("s_waitcnt lgkmcnt(" LG ")" ::: "memory");                   \
    __builtin_amdgcn_sched_barrier(0);                                        \
    __builtin_amdgcn_s_setprio(1);                                            \
    _Pragma("unroll")                                                         \
    for (int i_=0;i_<4;i_++)                                                  \
      _Pragma("unroll")                                                       \
      for (int j_=0;j_<4;j_++)                                                \
        acc[AH][i_][j_] = __builtin_amdgcn_mfma_f32_16x16x32_bf16(            \
            af[MFS][i_], bf[MBS][j_], acc[AH][i_][j_], 0,0,0);                \
    __builtin_amdgcn_s_setprio(0);                                            \
  }

  // prologue: stage tile 0 (FIFO unit order) into buf0; confirm u0-u2; pre-read ph0 frags
  STG_A(0,0,0,kstart); STG_B(0,0,0,kstart);
  STG_B(0,0,1,kstart); STG_A(0,0,1,kstart);
  STG_B(0,1,0,kstart); STG_B(0,1,1,kstart);
  STG_A(0,1,0,kstart); STG_A(0,1,1,kstart);
  asm volatile("s_waitcnt vmcnt(5)" ::: "memory");
  __builtin_amdgcn_s_barrier();
  ds_read128x4(a_rdB, af[0]);       // buf0, unit A(ks0,h0)
  ds_read128x4(b_rdB, bf[0]);       // buf0, unit B(ks0,bun)

  const int NT = K >> 6;                          // 16 for both GEMMs (even)
  for (int t=0; t<NT; t+=2){
    const int ka = kstart + (t+1)*64;                               // stage tile t+1
    const int kb = (t+2 < NT) ? (kstart + (t+2)*64) : kstart;       // stage tile t+2 / dummy
    // tile t in buf0, staging t+1 -> buf1
    PH(0,0,0, 0,0,1,0, "6","4", STG_A(1,0,0,ka); STG_B(1,0,0,ka));
    PH(1,0,1, 0,1,0,1, "5","8", STG_B(1,0,1,ka); STG_A(1,0,1,ka));
    PH(0,1,0, 0,1,1,0, "6","4", STG_B(1,1,0,ka); STG_B(1,1,1,ka));
    PH(1,1,1, 1,0,0,1, "5","8", STG_A(1,1,0,ka); STG_A(1,1,1,ka));
    // tile t+1 in buf1, staging t+2 -> buf0
    PH(0,0,0, 1,0,1,0, "6","4", STG_A(0,0,0,kb); STG_B(0,0,0,kb));
    PH(1,0,1, 1,1,0,1, "5","8", STG_B(0,0,1,kb); STG_A(0,0,1,kb));
    PH(0,1,0, 1,1,1,0, "6","4", STG_B(0,1,0,kb); STG_B(0,1,1,kb));
    PH(1,1,1, 0,0,0,1, "5","8", STG_A(0,1,0,kb); STG_A(0,1,1,kb));
  }

#undef PH
#undef STG_A
#undef STG_B

  #pragma unroll
  for (int h=0;h<2;h++){
    #pragma unroll
    for (int i=0;i<4;i++){
      #pragma unroll
      for (int j=0;j<4;j++){
        #pragma unroll
        for (int r=0;r<4;r++){
          int gr = m0 + h*128 + mq*64 + i*16 + quad*4 + r;
          int gc = n0 + nq*64 + j*16 + lr;
          float v = acc[h][i][j][r];
          size_t o = (size_t)gr*ldo + gc;
          if (EPI==2) outB[o] = f2b(geluf(v));
          else        outF[zstr*zb + o] = v;     // EPI==4 split-K partial store
        }
      }
    }
  }
}

// ---------------- chunked selective scan (32 chunks x 32 steps) ----------------
// chains: (b, d) = 4096. Lane owns (b, d, chunk), 16 n-states in registers.
// blk bits: [0:2)=d-block(4), [2:7)=chunk(32), [7:9)=b(4) -> grid 512
__global__ __launch_bounds__(256)
void scan_p1(const float* __restrict__ delta, const float* __restrict__ h0f,
             const float* __restrict__ BCf, const float* __restrict__ A_log,
             float* __restrict__ Pbuf, float* __restrict__ Sbuf)
{
  int blk = blockIdx.x;
  int d = (blk & 3)*256 + threadIdx.x;
  int c = (blk >> 2) & 31;
  int b = blk >> 7;
  float a2[16], h[16], P[16];
  #pragma unroll
  for (int n=0;n<16;n++){ a2[n] = -__expf(A_log[d*16+n]) * 1.44269504f; h[n]=0.f; P[n]=1.f; }
  int t0 = c*32;
  const float* dptr = delta + ((size_t)(b*1024 + t0))*1024 + d;
  const float* xptr = h0f   + ((size_t)(b*1024 + t0))*1024 + d;
  const float* bc   = BCf   + ((size_t)(b*1024 + t0))*32;
  #pragma unroll 4
  for (int t=0;t<32;t++){
    float dlt = dptr[t*1024];
    float xv  = xptr[t*1024];
    float dx = dlt*xv;
    #pragma unroll
    for (int n=0;n<16;n++){
      float dA = exp2f(dlt*a2[n]);
      h[n] = dA*h[n] + dx*bc[t*32+n];
      P[n] *= dA;
    }
  }
  size_t base = ((size_t)((b*32 + c)*16))*1024 + d;
  #pragma unroll
  for (int n=0;n<16;n++){ Pbuf[base + (size_t)n*1024] = P[n]; Sbuf[base + (size_t)n*1024] = h[n]; }
}

// blk bits: [0:2)=d-block(4), [2:6)=n(16), [6:8)=b(4) -> grid 256
// dependent-chain software pipeline: chunk c+1's P/S loads issue before chunk c's
// H-update, hiding one HBM latency per iteration (1 block/CU, latency-bound kernel).
__global__ __launch_bounds__(256)
void scan_p2(const float* __restrict__ Pbuf, const float* __restrict__ Sbuf,
             float* __restrict__ Hbuf)
{
  int blk = blockIdx.x;
  int d = (blk & 3)*256 + threadIdx.x;
  int n = (blk >> 2) & 15;
  int b = blk >> 6;
  const size_t cstr = (size_t)16*1024;
  size_t idx = ((size_t)((b*32 + 0)*16 + n))*1024 + d;
  float H = 0.f;
  float P = Pbuf[idx], S = Sbuf[idx];
  for (int c=0;c<32;c++){
    float Pn = 0.f, Sn = 0.f;
    if (c < 31){ Pn = Pbuf[idx + cstr]; Sn = Sbuf[idx + cstr]; }
    Hbuf[idx] = H;
    H = P*H + S;
    P = Pn; S = Sn;
    idx += cstr;
  }
}

// writes h1 directly into `out` (residual base; ln2 + proj_reduce read it there)
__global__ __launch_bounds__(256)
void scan_p3(const float* __restrict__ delta, const float* __restrict__ h0f,
             const float* __restrict__ BCf, const float* __restrict__ A_log,
             const float* __restrict__ Hbuf, const float* __restrict__ Dp,
             float* __restrict__ outp)
{
  int blk = blockIdx.x;
  int d = (blk & 3)*256 + threadIdx.x;
  int c = (blk >> 2) & 31;
  int b = blk >> 7;
  float a2[16], h[16];
  size_t hb = ((size_t)((b*32 + c)*16))*1024 + d;
  #pragma unroll
  for (int n=0;n<16;n++){
    a2[n] = -__expf(A_log[d*16+n]) * 1.44269504f;
    h[n] = Hbuf[hb + (size_t)n*1024];
  }
  float dpv = 1.f + Dp[d];
  int t0 = c*32;
  const float* dptr = delta + ((size_t)(b*1024 + t0))*1024 + d;
  const float* xptr = h0f   + ((size_t)(b*1024 + t0))*1024 + d;
  const float* bc   = BCf   + ((size_t)(b*1024 + t0))*32;
  float* wptr = outp + ((size_t)(b*1024 + t0))*1024 + d;
  #pragma unroll 4
  for (int t=0;t<32;t++){
    float dlt = dptr[t*1024];
    float xv  = xptr[t*1024];
    float dx = dlt*xv;
    float y = 0.f;
    #pragma unroll
    for (int n=0;n<16;n++){
      float dA = exp2f(dlt*a2[n]);
      h[n] = dA*h[n] + dx*bc[t*32+n];
      y += h[n]*bc[t*32+16+n];
    }
    wptr[t*1024] = xv*dpv + y;
  }
}

// ---------------- launch ----------------
extern "C" void kernel_launch(void* const* d_in, const int* in_sizes, int n_in,
                              void* d_out, int out_size, void* d_ws, size_t ws_size,
                              hipStream_t stream)
{
  const float* x    = (const float*)d_in[0];
  const float* ln1w = (const float*)d_in[1];
  const float* ln2w = (const float*)d_in[2];
  const float* Wdbc = (const float*)d_in[3];
  const float* Wdt  = (const float*)d_in[4];
  const float* bdt  = (const float*)d_in[5];
  const float* Alog = (const float*)d_in[6];
  const float* Dp   = (const float*)d_in[7];
  const float* Wfc  = (const float*)d_in[8];
  const float* Wproj= (const float*)d_in[9];
  float* out = (float*)d_out;

  char* ws = (char*)d_ws;
  size_t off = 0;
  auto carve = [&](size_t bytes)->char*{ char* p = ws + off; off += (bytes + 255) & ~(size_t)255; return p; };
  const size_t T = 4096;                       // B*L tokens
  float* h0f   = (float*)carve(T*1024*4);
  float* dlt   = (float*)carve(T*1024*4);
  float* Pbuf  = (float*)carve((size_t)4*32*16*1024*4);   // 8MB
  float* Sbuf  = (float*)carve((size_t)4*32*16*1024*4);   // 8MB
  float* Hbuf  = (float*)carve((size_t)4*32*16*1024*4);   // 8MB
  float* pad_  = (float*)carve((size_t)4*32*16*1024*4);   // 8MB (alias space)
  float* BCf   = (float*)carve(T*32*4);
  u16*   h0b   = (u16*)  carve(T*1024*2);
  u16*   m0b   = (u16*)  carve(T*1024*2);
  u16*   g_b   = (u16*)  carve(T*4096*2);
  u16*   din_b = (u16*)  carve(T*64*2);
  u16*   Wdbc_b= (u16*)  carve((size_t)128*1024*2);
  u16*   Wdt_b = (u16*)  carve((size_t)1024*64*2);
  u16*   Wfc_b = (u16*)  carve((size_t)4096*1024*2);
  u16*   Wpj_b = (u16*)  carve((size_t)1024*4096*2);
  // lifetime-disjoint aliases:
  float* dbc_p  = Hbuf;   // 8 x 4096x128 f32 = 16MB (Hbuf+pad_); dead before scan_p2 writes Hbuf
  // proj split-K=4 partials: 4 x 16MB = 64MB over the contiguous dead region
  // [dlt, Pbuf, Sbuf, Hbuf, pad_, BCf, h0b, m0b] (all dead after scan_p3 / FC gemm).
  float* proj_p = dlt;
  (void)pad_; (void)ws_size; (void)in_sizes; (void)n_in; (void)out_size;

  // fused head: weight casts + LN1 (independent DAG heads, one launch)
  prep_ln1<<<12480, 256, 0, stream>>>(Wdbc, Wdt, Wfc, Wproj,
                                      Wdbc_b, Wdt_b, Wfc_b, Wpj_b,
                                      x, ln1w, h0f, h0b);

  // dbc = h0 @ W_dbc^T  (N padded to 128), split-K=8 f32 partials
  gemm_bt<4,0><<<dim3(1,32,8), 256, 0, stream>>>(h0b, 1024, Wdbc_b, 1024, 128,
                                                 dbc_p, nullptr, 128, nullptr, (size_t)T*128);
  // reduce partials -> delta-input bf16 + B/C f32
  dbc_post<<<2048, 256, 0, stream>>>(dbc_p, din_b, BCf);

  // delta = softplus(din @ W_dt^T + b_dt), f32 out
  gemm_bt<1,0><<<dim3(8,32), 256, 0, stream>>>(din_b, 64, Wdt_b, 64, 64,
                                               dlt, nullptr, 1024, bdt, 0);

  // selective scan -> out = h1 = h0*(1+Dp) + y  (residual base; ln2 reads it)
  scan_p1<<<512, 256, 0, stream>>>(dlt, h0f, BCf, Alog, Pbuf, Sbuf);
  scan_p2<<<256, 256, 0, stream>>>(Pbuf, Sbuf, Hbuf);
  scan_p3<<<512, 256, 0, stream>>>(dlt, h0f, BCf, Alog, Hbuf, Dp, out);

  // m0 = LN2(h1) (bf16) — reads h1 from out
  ln2_kernel<<<4096, 256, 0, stream>>>(out, ln2w, m0b);

  // g = gelu(m0 @ W_fc^T) (bf16) — 256^2 pipelined (asm ds_read), XCD supertiled
  gemm256<2,3><<<256, 512, 0, stream>>>(m0b, 1024, Wfc_b, 1024, 1024,
                                        nullptr, g_b, 4096, 0);

  // proj partials: g @ W_proj^T, split-K=4 f32 partials (round-4/7 proven structure)
  gemm256<4,4><<<256, 512, 0, stream>>>(g_b, 4096, Wpj_b, 4096, 1024,
                                        proj_p, nullptr, 1024, (size_t)T*1024);
  // out = p0+p1+p2+p3 + out (residual already in out)
  proj_reduce<<<4096, 256, 0, stream>>>(proj_p, out);
}

// Round 11
// 318.020 us; speedup vs baseline: 1.5328x; 1.0224x over previous
//
#include <hip/hip_runtime.h>
#include <cstdint>
#include <cstddef>

typedef unsigned short u16;
typedef unsigned int u32;
typedef __attribute__((ext_vector_type(8))) short short8;
typedef __attribute__((ext_vector_type(4))) float floatx4;
typedef __attribute__((ext_vector_type(4))) u16 u16x4;
typedef __attribute__((ext_vector_type(4))) u32 u32x4;

#define DEV static __device__ __forceinline__

DEV u16 f2b(float f){ u32 u = __float_as_uint(f); u32 r = u + 0x7fffu + ((u>>16)&1u); return (u16)(r>>16); }
DEV float b2f(u16 h){ return __uint_as_float(((u32)h)<<16); }
DEV float softplusf(float z){ return fmaxf(z,0.f) + log1pf(__expf(-fabsf(z))); }
DEV float fast_tanhf(float u){ float e = __expf(2.f*u); return 1.f - 2.f/(e+1.f); }
DEV float geluf(float x){ float u = 0.7978845608028654f*(x + 0.044715f*x*x*x); return 0.5f*x*(1.f+fast_tanhf(u)); }

DEV void async_copy16(const void* gp, void* lp){
  __builtin_amdgcn_global_load_lds((const __attribute__((address_space(1))) u32*)gp,
                                   (__attribute__((address_space(3))) u32*)lp, 16, 0, 0);
}

// LDS byte offset of a generic pointer to __shared__ (AS3 ptrs are 32-bit offsets)
DEV u32 ldsoff(const void* p){
  return (u32)(size_t)(const __attribute__((address_space(3))) char*)p;
}

// 4x ds_read_b128 with immediate offsets, OPAQUE to the compiler's waitcnt pass:
// ordering vs in-flight global_load_lds is done by OUR counted vmcnt/lgkmcnt + barriers.
DEV void ds_read128x4(u32 base, short8* dst){
  u32x4 r0, r1, r2, r3;
  asm volatile("ds_read_b128 %0, %4 offset:0\n\t"
               "ds_read_b128 %1, %4 offset:1024\n\t"
               "ds_read_b128 %2, %4 offset:2048\n\t"
               "ds_read_b128 %3, %4 offset:3072"
               : "=&v"(r0), "=&v"(r1), "=&v"(r2), "=&v"(r3)
               : "v"(base));
  union { u32x4 u; short8 s; } c0, c1, c2, c3;
  c0.u = r0; c1.u = r1; c2.u = r2; c3.u = r3;
  dst[0] = c0.s; dst[1] = c1.s; dst[2] = c2.s; dst[3] = c3.s;
}

// ---------------- fused head: all four weight casts + LN1, one launch ----------------
// blocks [0,8384): weight cast (float4 per thread).  blocks [8384,12480): LN1 rows.
__global__ __launch_bounds__(256)
void prep_ln1(const float* __restrict__ Wdbc, const float* __restrict__ Wdt,
              const float* __restrict__ Wfc, const float* __restrict__ Wproj,
              u16* __restrict__ dbc_b, u16* __restrict__ dt_b,
              u16* __restrict__ fc_b, u16* __restrict__ pj_b,
              const float* __restrict__ x, const float* __restrict__ ln1w,
              float* __restrict__ h0f, u16* __restrict__ h0b)
{
  __shared__ float red[8];
  int bx = blockIdx.x, tid = threadIdx.x;
  if (bx < 8384){
    int i = bx*256 + tid;
    const float* src; u16* dst; int j;
    if (i < 32768){
      int e = i*4, r = e >> 10;
      if (r >= 96){ u16x4 z = {0,0,0,0}; *(u16x4*)(dbc_b + e) = z; return; }
      src = Wdbc; dst = dbc_b; j = i;
    } else if (i < 49152){ src = Wdt;   dst = dt_b; j = i - 32768; }
    else if (i < 1097728){ src = Wfc;   dst = fc_b; j = i - 49152; }
    else                 { src = Wproj; dst = pj_b; j = i - 1097728; }
    float4 v = ((const float4*)src)[j];
    u16x4 o = { f2b(v.x), f2b(v.y), f2b(v.z), f2b(v.w) };
    *(u16x4*)(dst + j*4) = o;
    return;
  }
  int row = bx - 8384;
  const float4* xr = (const float4*)(x + (size_t)row*1024);
  float4 v = xr[tid];
  float s1 = v.x+v.y+v.z+v.w;
  float s2 = v.x*v.x+v.y*v.y+v.z*v.z+v.w*v.w;
  #pragma unroll
  for (int m=1;m<64;m<<=1){ s1 += __shfl_xor(s1,m); s2 += __shfl_xor(s2,m); }
  int wv = tid>>6;
  if ((tid&63)==0){ red[wv]=s1; red[4+wv]=s2; }
  __syncthreads();
  s1 = red[0]+red[1]+red[2]+red[3];
  s2 = red[4]+red[5]+red[6]+red[7];
  float mu  = s1*(1.f/1024.f);
  float var = s2*(1.f/1024.f) - mu*mu;
  float rstd = rsqrtf(var + 1e-5f);
  float4 wv4 = ((const float4*)ln1w)[tid];
  float o0 = softplusf((v.x-mu)*rstd*wv4.x);
  float o1 = softplusf((v.y-mu)*rstd*wv4.y);
  float o2 = softplusf((v.z-mu)*rstd*wv4.z);
  float o3 = softplusf((v.w-mu)*rstd*wv4.w);
  ((float4*)(h0f + (size_t)row*1024))[tid] = make_float4(o0,o1,o2,o3);
  u16x4 ob = { f2b(o0), f2b(o1), f2b(o2), f2b(o3) };
  *(u16x4*)(h0b + (size_t)row*1024 + tid*4) = ob;
}

// reduce 8 dbc split-K partials -> delta-GEMM bf16 input (cols 0..63) + f32 B/C buffer (cols 64..95)
__global__ void dbc_post(const float* __restrict__ p, u16* __restrict__ delta_in,
                         float* __restrict__ BCf){
  int e = blockIdx.x*256 + threadIdx.x;          // 524288 = 4096*128
  int t = e >> 7, c = e & 127;
  float s = 0.f;
  #pragma unroll
  for (int z=0;z<8;z++) s += p[(size_t)z*524288 + e];
  if (c < 64)      delta_in[t*64 + c] = f2b(s);
  else if (c < 96) BCf[t*32 + (c-64)] = s;
}

// out = p0+p1+p2+p3 + out  (proj split-K=4 reduce over BF16 partials; out holds h1)
// partials: 4 slices of 4M bf16 at z-stride 4194304 elements. 8 elems/thread, grid 2048.
__global__ void proj_reduce(const u16* __restrict__ p, float* __restrict__ out){
  int i = blockIdx.x*256 + threadIdx.x;          // over 512K groups of 8
  short8 a = ((const short8*)p)[i];
  short8 b = ((const short8*)(p + (size_t) 4194304))[i];
  short8 c = ((const short8*)(p + (size_t) 8388608))[i];
  short8 d = ((const short8*)(p + (size_t)12582912))[i];
  float4 r0 = ((const float4*)out)[i*2+0];
  float4 r1 = ((const float4*)out)[i*2+1];
  float s[8];
  #pragma unroll
  for (int k=0;k<8;k++)
    s[k] = b2f((u16)a[k]) + b2f((u16)b[k]) + b2f((u16)c[k]) + b2f((u16)d[k]);
  ((float4*)out)[i*2+0] = make_float4(s[0]+r0.x, s[1]+r0.y, s[2]+r0.z, s[3]+r0.w);
  ((float4*)out)[i*2+1] = make_float4(s[4]+r1.x, s[5]+r1.y, s[6]+r1.z, s[7]+r1.w);
}

__global__ __launch_bounds__(256)
void ln2_kernel(const float* __restrict__ x, const float* __restrict__ w,
                u16* __restrict__ outb)
{
  int row = blockIdx.x, tid = threadIdx.x;
  const float4* xr = (const float4*)(x + (size_t)row*1024);
  float4 v = xr[tid];
  float s1 = v.x+v.y+v.z+v.w;
  float s2 = v.x*v.x+v.y*v.y+v.z*v.z+v.w*v.w;
  #pragma unroll
  for (int m=1;m<64;m<<=1){ s1 += __shfl_xor(s1,m); s2 += __shfl_xor(s2,m); }
  __shared__ float red[8];
  int wv = tid>>6;
  if ((tid&63)==0){ red[wv]=s1; red[4+wv]=s2; }
  __syncthreads();
  s1 = red[0]+red[1]+red[2]+red[3];
  s2 = red[4]+red[5]+red[6]+red[7];
  float mu  = s1*(1.f/1024.f);
  float var = s2*(1.f/1024.f) - mu*mu;
  float rstd = rsqrtf(var + 1e-5f);
  float4 wv4 = ((const float4*)w)[tid];
  u16x4 ob = { f2b((v.x-mu)*rstd*wv4.x), f2b((v.y-mu)*rstd*wv4.y),
               f2b((v.z-mu)*rstd*wv4.z), f2b((v.w-mu)*rstd*wv4.w) };
  *(u16x4*)(outb + (size_t)row*1024 + tid*4) = ob;
}

// ---------------- MFMA GEMM (128x128, 2-barrier) — kept for the small GEMMs ----------------
template<int EPI, int SWZ>
__global__ __launch_bounds__(256)
void gemm_bt(const u16* __restrict__ A, int lda,
             const u16* __restrict__ B, int ldb, int K,
             float* __restrict__ outF, u16* __restrict__ outB, int ldo,
             const float* __restrict__ bias, size_t zstr)
{
  __shared__ u16 sA[128*32];
  __shared__ u16 sB[128*32];
  const int tid = threadIdx.x;
  int m_blk, n_blk, zb;
  if (SWZ == 0){ n_blk = blockIdx.x; m_blk = blockIdx.y; zb = blockIdx.z; }
  else if (SWZ == 1){
    int b = blockIdx.x, xcd = b & 7, local = b >> 3;
    m_blk = (xcd>>2)*16 + (local & 15);
    n_blk = (xcd&3)*8 + (local >> 4);
    zb = 0;
  } else {
    int b = blockIdx.x, xcd = b & 7, local = b >> 3;
    m_blk = (xcd>>1)*8 + (local & 7);
    n_blk = local >> 3;
    zb = xcd & 1;
  }
  const int m0 = m_blk*128, n0 = n_blk*128;
  const int kstart = zb * K;
  const int wave = tid>>6, lane = tid&63;
  const int wm = (wave>>1)*64, wn = (wave&1)*64;
  const int lr = lane&15, quad = lane>>4;

  floatx4 acc[4][4];
  #pragma unroll
  for (int i=0;i<4;i++)
    #pragma unroll
    for (int j=0;j<4;j++){ floatx4 z = {0.f,0.f,0.f,0.f}; acc[i][j]=z; }

  const int r0 = tid>>2;
  const int kc8 = (((tid&3) ^ ((tid>>3)&3)))*8;   // swizzled source k-offset (u16 units)
  const int sswz = ((lr>>1)&3);                    // reader slot xor term
  for (int k0=kstart; k0<kstart+K; k0+=32){
    __syncthreads();
    async_copy16(A + (size_t)(m0+r0)*lda    + k0+kc8, &sA[(size_t)tid*8]);
    async_copy16(A + (size_t)(m0+64+r0)*lda + k0+kc8, &sA[(size_t)(tid+256)*8]);
    async_copy16(B + (size_t)(n0+r0)*ldb    + k0+kc8, &sB[(size_t)tid*8]);
    async_copy16(B + (size_t)(n0+64+r0)*ldb + k0+kc8, &sB[(size_t)(tid+256)*8]);
    __syncthreads();
    short8 af[4], bf[4];
    #pragma unroll
    for (int i=0;i<4;i++){
      af[i] = *(const short8*)&sA[(wm+i*16+lr)*32 + (quad^sswz)*8];
      bf[i] = *(const short8*)&sB[(wn+i*16+lr)*32 + (quad^sswz)*8];
    }
    #pragma unroll
    for (int i=0;i<4;i++)
      #pragma unroll
      for (int j=0;j<4;j++)
        acc[i][j] = __builtin_amdgcn_mfma_f32_16x16x32_bf16(af[i], bf[j], acc[i][j], 0,0,0);
  }
  #pragma unroll
  for (int i=0;i<4;i++){
    #pragma unroll
    for (int j=0;j<4;j++){
      #pragma unroll
      for (int r=0;r<4;r++){
        int gr = m0 + wm + i*16 + quad*4 + r;
        int gc = n0 + wn + j*16 + lr;
        float v = acc[i][j][r];
        size_t o = (size_t)gr*ldo + gc;
        if (EPI==1)      outF[o] = softplusf(v + bias[gc]);
        else if (EPI==2) outB[o] = f2b(geluf(v));
        else             outF[zstr*zb + o] = v;
      }
    }
  }
}

// ---------------- 256x256 pipelined GEMM: asm ds_read + frag read-ahead + counted vmcnt --
// (round-7 proven structure; 44us / MfmaUtil 31% on FC and proj at K=1024)
// EPI 2: gelu->bf16 store.  EPI 4: BF16 split-K partial store to outB at zstr*zb
// (halves the partial stream; rounding ~3e-3 abs, 20x below current error level).
// Last-tile dummy stages target tile NT-1's addresses (L2-hot, just fetched) instead of
// kstart (L2-cold) — cuts ~8MB/dispatch of dummy HBM FETCH; data never consumed.
// NO atomics / NO intra-kernel cross-block reduction (r5/r6/r8 failures — see history).
// SWZ 3: FC 16x16 blocks, XCD supertile 8m x 4n.
// SWZ 4: proj — zb=xcd>>1, m=(xcd&1)*8+(local&7), n=local>>3.
template<int EPI, int SWZ>
__global__ __launch_bounds__(512, 2)
void gemm256(const u16* __restrict__ A, int lda,
             const u16* __restrict__ B, int ldb, int K,
             u16* __restrict__ outB, int ldo, size_t zstr)
{
  __shared__ u16 sA[2][4][4096];   // [buf][unit=ks*2+half][128*32]
  __shared__ u16 sB[2][4][4096];
  const int tid = threadIdx.x;
  int m_blk, n_blk, zb;
  if (SWZ == 3){
    int b = blockIdx.x, xcd = b & 7, local = b >> 3;
    m_blk = (xcd>>2)*8 + (local & 7);
    n_blk = (xcd&3)*4 + (local >> 3);
    zb = 0;
  } else {
    int b = blockIdx.x, xcd = b & 7, local = b >> 3;
    zb    = xcd >> 1;
    m_blk = (xcd&1)*8 + (local & 7);
    n_blk = local >> 3;
  }
  const int m0 = m_blk*256, n0 = n_blk*256;
  const int kstart = zb*K;
  const int wave = tid>>6, lane = tid&63;
  const int mq = wave>>2, nq = wave&3;
  const int lr = lane&15, quad = lane>>4;
  const int sswz = (lr>>1)&3;

  // staging source addressing (pre-swizzled chunk, rule 21: linear LDS dest)
  const int srow = tid>>2;
  const int scol = ((tid&3) ^ ((tid>>3)&3))*8;
  const u16* pa = A + (size_t)(m0 + srow)*lda + scol;
  const u16* pb = B + (size_t)(n0 + srow)*ldb + scol;
  u16* la = (u16*)sA + tid*8;
  u16* lb = (u16*)sB + tid*8;
  const size_t ah128 = (size_t)128*lda;
  const size_t bh128 = (size_t)128*ldb;

  // reader bases (u16 offsets inside one buffer)
  const int a_rd = (mq*64 + lr)*32 + (quad^sswz)*8;
  const int b_rd = ((nq&1)*64 + lr)*32 + (quad^sswz)*8;
  const int bun  = nq>>1;                       // B row-half this wave reads
  // asm ds_read byte-offset bases (unit byte off = BUF*32768 + KS*16384 + H*8192)
  const u32 a_rdB = ldsoff(sA) + (u32)(a_rd*2);
  const u32 b_rdB = ldsoff(sB) + (u32)(b_rd*2) + (u32)(bun*8192);

  floatx4 acc[2][4][4];
  #pragma unroll
  for (int h=0;h<2;h++)
    #pragma unroll
    for (int i=0;i<4;i++)
      #pragma unroll
      for (int j=0;j<4;j++){ floatx4 z={0.f,0.f,0.f,0.f}; acc[h][i][j]=z; }

  short8 af[2][4], bf[2][4];

#define STG_A(NB,KS,H,KT) async_copy16(pa + (size_t)(H)*ah128 + (size_t)((KT) + (KS)*32), \
                                       la + (NB)*16384 + ((KS)*2+(H))*4096)
#define STG_B(NB,KS,H,KT) async_copy16(pb + (size_t)(H)*bh128 + (size_t)((KT) + (KS)*32), \
                                       lb + (NB)*16384 + ((KS)*2+(H))*4096)

// MFS/MBS: frag sets consumed by this phase's MFMA; AH: acc row-half.
// PRBUF/PRKS/PRAH: unit for next phase's A pre-read (into af[MFS^1]);
// PRB: also pre-read B unit (PRKS,bun) into bf[MBS^1].
#define PH(MFS, MBS, AH, PRBUF, PRKS, PRAH, PRB, VM, LG, STMTS)               \
  {                                                                           \
    STMTS;                                                                    \
    asm volatile("s_waitcnt vmcnt(" VM ")" ::: "memory");                     \
    __builtin_amdgcn_s_barrier();                                             \
    ds_read128x4(a_rdB + (PRBUF)*32768u + (PRKS)*16384u + (PRAH)*8192u,       \
                 af[(MFS)^1]);                                                \
    if (PRB)                                                                  \
      ds_read128x4(b_rdB + (PRBUF)*32768u + (PRKS)*16384u, bf[(MBS)^1]);      \
    asm volatile("s_waitcnt lgkmcnt(" LG ")" ::: "memory");                   \
    __builtin_amdgcn_sched_barrier(0);                                        \
    __builtin_amdgcn_s_setprio(1);                                            \
    _Pragma("unroll")                                                         \
    for (int i_=0;i_<4;i_++)                                                  \
      _Pragma("unroll")                                                       \
      for (int j_=0;j_<4;j_++)                                                \
        acc[AH][i_][j_] = __builtin_amdgcn_mfma_f32_16x16x32_bf16(            \
            af[MFS][i_], bf[MBS][j_], acc[AH][i_][j_], 0,0,0);                \
    __builtin_amdgcn_s_setprio(0);                                            \
  }

  // prologue: stage tile 0 (FIFO unit order) into buf0; confirm u0-u2; pre-read ph0 frags
  STG_A(0,0,0,kstart); STG_B(0,0,0,kstart);
  STG_B(0,0,1,kstart); STG_A(0,0,1,kstart);
  STG_B(0,1,0,kstart); STG_B(0,1,1,kstart);
  STG_A(0,1,0,kstart); STG_A(0,1,1,kstart);
  asm volatile("s_waitcnt vmcnt(5)" ::: "memory");
  __builtin_amdgcn_s_barrier();
  ds_read128x4(a_rdB, af[0]);       // buf0, unit A(ks0,h0)
  ds_read128x4(b_rdB, bf[0]);       // buf0, unit B(ks0,bun)

  const int NT = K >> 6;                          // 16 for both GEMMs (even)
  for (int t=0; t<NT; t+=2){
    const int ka = kstart + (t+1)*64;                         // stage tile t+1
    const int kb = (t+2 < NT) ? (kstart + (t+2)*64) : ka;     // t+2, or L2-HOT dummy (=ka)
    // tile t in buf0, staging t+1 -> buf1
    PH(0,0,0, 0,0,1,0, "6","4", STG_A(1,0,0,ka); STG_B(1,0,0,ka));
    PH(1,0,1, 0,1,0,1, "5","8", STG_B(1,0,1,ka); STG_A(1,0,1,ka));
    PH(0,1,0, 0,1,1,0, "6","4", STG_B(1,1,0,ka); STG_B(1,1,1,ka));
    PH(1,1,1, 1,0,0,1, "5","8", STG_A(1,1,0,ka); STG_A(1,1,1,ka));
    // tile t+1 in buf1, staging t+2 -> buf0
    PH(0,0,0, 1,0,1,0, "6","4", STG_A(0,0,0,kb); STG_B(0,0,0,kb));
    PH(1,0,1, 1,1,0,1, "5","8", STG_B(0,0,1,kb); STG_A(0,0,1,kb));
    PH(0,1,0, 1,1,1,0, "6","4", STG_B(0,1,0,kb); STG_B(0,1,1,kb));
    PH(1,1,1, 0,0,0,1, "5","8", STG_A(0,1,0,kb); STG_A(0,1,1,kb));
  }

#undef PH
#undef STG_A
#undef STG_B

  #pragma unroll
  for (int h=0;h<2;h++){
    #pragma unroll
    for (int i=0;i<4;i++){
      #pragma unroll
      for (int j=0;j<4;j++){
        #pragma unroll
        for (int r=0;r<4;r++){
          int gr = m0 + h*128 + mq*64 + i*16 + quad*4 + r;
          int gc = n0 + nq*64 + j*16 + lr;
          float v = acc[h][i][j][r];
          size_t o = (size_t)gr*ldo + gc;
          if (EPI==2) outB[o] = f2b(geluf(v));
          else        outB[zstr*zb + o] = f2b(v);   // EPI==4 bf16 split-K partial
        }
      }
    }
  }
}

// ---------------- chunked selective scan (32 chunks x 32 steps) ----------------
// chains: (b, d) = 4096. Lane owns (b, d, chunk), 16 n-states in registers.
// blk bits: [0:2)=d-block(4), [2:7)=chunk(32), [7:9)=b(4) -> grid 512
__global__ __launch_bounds__(256)
void scan_p1(const float* __restrict__ delta, const float* __restrict__ h0f,
             const float* __restrict__ BCf, const float* __restrict__ A_log,
             float* __restrict__ Pbuf, float* __restrict__ Sbuf)
{
  int blk = blockIdx.x;
  int d = (blk & 3)*256 + threadIdx.x;
  int c = (blk >> 2) & 31;
  int b = blk >> 7;
  float a2[16], h[16], P[16];
  #pragma unroll
  for (int n=0;n<16;n++){ a2[n] = -__expf(A_log[d*16+n]) * 1.44269504f; h[n]=0.f; P[n]=1.f; }
  int t0 = c*32;
  const float* dptr = delta + ((size_t)(b*1024 + t0))*1024 + d;
  const float* xptr = h0f   + ((size_t)(b*1024 + t0))*1024 + d;
  const float* bc   = BCf   + ((size_t)(b*1024 + t0))*32;
  #pragma unroll 4
  for (int t=0;t<32;t++){
    float dlt = dptr[t*1024];
    float xv  = xptr[t*1024];
    float dx = dlt*xv;
    #pragma unroll
    for (int n=0;n<16;n++){
      float dA = exp2f(dlt*a2[n]);
      h[n] = dA*h[n] + dx*bc[t*32+n];
      P[n] *= dA;
    }
  }
  size_t base = ((size_t)((b*32 + c)*16))*1024 + d;
  #pragma unroll
  for (int n=0;n<16;n++){ Pbuf[base + (size_t)n*1024] = P[n]; Sbuf[base + (size_t)n*1024] = h[n]; }
}

// blk bits: [0:2)=d-block(4), [2:6)=n(16), [6:8)=b(4) -> grid 256
// dependent-chain software pipeline: chunk c+1's P/S loads issue before chunk c's
// H-update, hiding one HBM latency per iteration (1 block/CU, latency-bound kernel).
__global__ __launch_bounds__(256)
void scan_p2(const float* __restrict__ Pbuf, const float* __restrict__ Sbuf,
             float* __restrict__ Hbuf)
{
  int blk = blockIdx.x;
  int d = (blk & 3)*256 + threadIdx.x;
  int n = (blk >> 2) & 15;
  int b = blk >> 6;
  const size_t cstr = (size_t)16*1024;
  size_t idx = ((size_t)((b*32 + 0)*16 + n))*1024 + d;
  float H = 0.f;
  float P = Pbuf[idx], S = Sbuf[idx];
  for (int c=0;c<32;c++){
    float Pn = 0.f, Sn = 0.f;
    if (c < 31){ Pn = Pbuf[idx + cstr]; Sn = Sbuf[idx + cstr]; }
    Hbuf[idx] = H;
    H = P*H + S;
    P = Pn; S = Sn;
    idx += cstr;
  }
}

// writes h1 directly into `out` (residual base; ln2 + proj_reduce read it there)
__global__ __launch_bounds__(256)
void scan_p3(const float* __restrict__ delta, const float* __restrict__ h0f,
             const float* __restrict__ BCf, const float* __restrict__ A_log,
             const float* __restrict__ Hbuf, const float* __restrict__ Dp,
             float* __restrict__ outp)
{
  int blk = blockIdx.x;
  int d = (blk & 3)*256 + threadIdx.x;
  int c = (blk >> 2) & 31;
  int b = blk >> 7;
  float a2[16], h[16];
  size_t hb = ((size_t)((b*32 + c)*16))*1024 + d;
  #pragma unroll
  for (int n=0;n<16;n++){
    a2[n] = -__expf(A_log[d*16+n]) * 1.44269504f;
    h[n] = Hbuf[hb + (size_t)n*1024];
  }
  float dpv = 1.f + Dp[d];
  int t0 = c*32;
  const float* dptr = delta + ((size_t)(b*1024 + t0))*1024 + d;
  const float* xptr = h0f   + ((size_t)(b*1024 + t0))*1024 + d;
  const float* bc   = BCf   + ((size_t)(b*1024 + t0))*32;
  float* wptr = outp + ((size_t)(b*1024 + t0))*1024 + d;
  #pragma unroll 4
  for (int t=0;t<32;t++){
    float dlt = dptr[t*1024];
    float xv  = xptr[t*1024];
    float dx = dlt*xv;
    float y = 0.f;
    #pragma unroll
    for (int n=0;n<16;n++){
      float dA = exp2f(dlt*a2[n]);
      h[n] = dA*h[n] + dx*bc[t*32+n];
      y += h[n]*bc[t*32+16+n];
    }
    wptr[t*1024] = xv*dpv + y;
  }
}

// ---------------- launch ----------------
extern "C" void kernel_launch(void* const* d_in, const int* in_sizes, int n_in,
                              void* d_out, int out_size, void* d_ws, size_t ws_size,
                              hipStream_t stream)
{
  const float* x    = (const float*)d_in[0];
  const float* ln1w = (const float*)d_in[1];
  const float* ln2w = (const float*)d_in[2];
  const float* Wdbc = (const float*)d_in[3];
  const float* Wdt  = (const float*)d_in[4];
  const float* bdt  = (const float*)d_in[5];
  const float* Alog = (const float*)d_in[6];
  const float* Dp   = (const float*)d_in[7];
  const float* Wfc  = (const float*)d_in[8];
  const float* Wproj= (const float*)d_in[9];
  float* out = (float*)d_out;

  char* ws = (char*)d_ws;
  size_t off = 0;
  auto carve = [&](size_t bytes)->char*{ char* p = ws + off; off += (bytes + 255) & ~(size_t)255; return p; };
  const size_t T = 4096;                       // B*L tokens
  float* h0f   = (float*)carve(T*1024*4);
  float* dlt   = (float*)carve(T*1024*4);
  float* Pbuf  = (float*)carve((size_t)4*32*16*1024*4);   // 8MB
  float* Sbuf  = (float*)carve((size_t)4*32*16*1024*4);   // 8MB
  float* Hbuf  = (float*)carve((size_t)4*32*16*1024*4);   // 8MB
  float* pad_  = (float*)carve((size_t)4*32*16*1024*4);   // 8MB (alias space)
  float* BCf   = (float*)carve(T*32*4);
  u16*   h0b   = (u16*)  carve(T*1024*2);
  u16*   m0b   = (u16*)  carve(T*1024*2);
  u16*   g_b   = (u16*)  carve(T*4096*2);
  u16*   din_b = (u16*)  carve(T*64*2);
  u16*   Wdbc_b= (u16*)  carve((size_t)128*1024*2);
  u16*   Wdt_b = (u16*)  carve((size_t)1024*64*2);
  u16*   Wfc_b = (u16*)  carve((size_t)4096*1024*2);
  u16*   Wpj_b = (u16*)  carve((size_t)1024*4096*2);
  // lifetime-disjoint aliases:
  float* dbc_p  = Hbuf;   // 8 x 4096x128 f32 = 16MB (Hbuf+pad_); dead before scan_p2 writes Hbuf
  // proj split-K=4 BF16 partials: 4 x 4M x 2B = 32MiB over [dlt, Pbuf, Sbuf] (exactly
  // 32MiB contiguous; all dead after scan_p3).
  u16* proj_p = (u16*)dlt;
  (void)pad_; (void)ws_size; (void)in_sizes; (void)n_in; (void)out_size;

  // fused head: weight casts + LN1 (independent DAG heads, one launch)
  prep_ln1<<<12480, 256, 0, stream>>>(Wdbc, Wdt, Wfc, Wproj,
                                      Wdbc_b, Wdt_b, Wfc_b, Wpj_b,
                                      x, ln1w, h0f, h0b);

  // dbc = h0 @ W_dbc^T  (N padded to 128), split-K=8 f32 partials
  gemm_bt<4,0><<<dim3(1,32,8), 256, 0, stream>>>(h0b, 1024, Wdbc_b, 1024, 128,
                                                 dbc_p, nullptr, 128, nullptr, (size_t)T*128);
  // reduce partials -> delta-input bf16 + B/C f32
  dbc_post<<<2048, 256, 0, stream>>>(dbc_p, din_b, BCf);

  // delta = softplus(din @ W_dt^T + b_dt), f32 out
  gemm_bt<1,0><<<dim3(8,32), 256, 0, stream>>>(din_b, 64, Wdt_b, 64, 64,
                                               dlt, nullptr, 1024, bdt, 0);

  // selective scan -> out = h1 = h0*(1+Dp) + y  (residual base; ln2 reads it)
  scan_p1<<<512, 256, 0, stream>>>(dlt, h0f, BCf, Alog, Pbuf, Sbuf);
  scan_p2<<<256, 256, 0, stream>>>(Pbuf, Sbuf, Hbuf);
  scan_p3<<<512, 256, 0, stream>>>(dlt, h0f, BCf, Alog, Hbuf, Dp, out);

  // m0 = LN2(h1) (bf16) — reads h1 from out
  ln2_kernel<<<4096, 256, 0, stream>>>(out, ln2w, m0b);

  // g = gelu(m0 @ W_fc^T) (bf16) — 256^2 pipelined (asm ds_read), XCD supertiled
  gemm256<2,3><<<256, 512, 0, stream>>>(m0b, 1024, Wfc_b, 1024, 1024,
                                        g_b, 4096, 0);

  // proj partials: g @ W_proj^T, split-K=4 BF16 partials
  gemm256<4,4><<<256, 512, 0, stream>>>(g_b, 4096, Wpj_b, 4096, 1024,
                                        proj_p, 1024, (size_t)T*1024);
  // out = p0+p1+p2+p3 + out (residual already in out)
  proj_reduce<<<2048, 256, 0, stream>>>(proj_p, out);
}

// Round 12
// 304.233 us; speedup vs baseline: 1.6023x; 1.0453x over previous
//
#include <hip/hip_runtime.h>
#include <cstdint>
#include <cstddef>

typedef unsigned short u16;
typedef unsigned int u32;
typedef __attribute__((ext_vector_type(8))) short short8;
typedef __attribute__((ext_vector_type(4))) float floatx4;
typedef __attribute__((ext_vector_type(4))) u16 u16x4;
typedef __attribute__((ext_vector_type(4))) u32 u32x4;

#define DEV static __device__ __forceinline__

DEV u16 f2b(float f){ u32 u = __float_as_uint(f); u32 r = u + 0x7fffu + ((u>>16)&1u); return (u16)(r>>16); }
DEV float b2f(u16 h){ return __uint_as_float(((u32)h)<<16); }
DEV float softplusf(float z){ return fmaxf(z,0.f) + log1pf(__expf(-fabsf(z))); }
DEV float fast_tanhf(float u){ float e = __expf(2.f*u); return 1.f - 2.f/(e+1.f); }
DEV float geluf(float x){ float u = 0.7978845608028654f*(x + 0.044715f*x*x*x); return 0.5f*x*(1.f+fast_tanhf(u)); }

DEV void async_copy16(const void* gp, void* lp){
  __builtin_amdgcn_global_load_lds((const __attribute__((address_space(1))) u32*)gp,
                                   (__attribute__((address_space(3))) u32*)lp, 16, 0, 0);
}

// LDS byte offset of a generic pointer to __shared__ (AS3 ptrs are 32-bit offsets)
DEV u32 ldsoff(const void* p){
  return (u32)(size_t)(const __attribute__((address_space(3))) char*)p;
}

// 4x ds_read_b128 with immediate offsets, OPAQUE to the compiler's waitcnt pass:
// ordering vs in-flight global_load_lds is done by OUR counted vmcnt/lgkmcnt + barriers.
DEV void ds_read128x4(u32 base, short8* dst){
  u32x4 r0, r1, r2, r3;
  asm volatile("ds_read_b128 %0, %4 offset:0\n\t"
               "ds_read_b128 %1, %4 offset:1024\n\t"
               "ds_read_b128 %2, %4 offset:2048\n\t"
               "ds_read_b128 %3, %4 offset:3072"
               : "=&v"(r0), "=&v"(r1), "=&v"(r2), "=&v"(r3)
               : "v"(base));
  union { u32x4 u; short8 s; } c0, c1, c2, c3;
  c0.u = r0; c1.u = r1; c2.u = r2; c3.u = r3;
  dst[0] = c0.s; dst[1] = c1.s; dst[2] = c2.s; dst[3] = c3.s;
}

// ---------------- fused head: all four weight casts + LN1, one launch ----------------
// blocks [0,8384): weight cast (float4 per thread).  blocks [8384,12480): LN1 rows.
// LN1 output is bf16-only (h0b) — the f32 copy was dropped: dbc GEMM consumed h0b
// already, and the scans now read h0b too (consistent with how delta was computed).
__global__ __launch_bounds__(256)
void prep_ln1(const float* __restrict__ Wdbc, const float* __restrict__ Wdt,
              const float* __restrict__ Wfc, const float* __restrict__ Wproj,
              u16* __restrict__ dbc_b, u16* __restrict__ dt_b,
              u16* __restrict__ fc_b, u16* __restrict__ pj_b,
              const float* __restrict__ x, const float* __restrict__ ln1w,
              u16* __restrict__ h0b)
{
  __shared__ float red[8];
  int bx = blockIdx.x, tid = threadIdx.x;
  if (bx < 8384){
    int i = bx*256 + tid;
    const float* src; u16* dst; int j;
    if (i < 32768){
      int e = i*4, r = e >> 10;
      if (r >= 96){ u16x4 z = {0,0,0,0}; *(u16x4*)(dbc_b + e) = z; return; }
      src = Wdbc; dst = dbc_b; j = i;
    } else if (i < 49152){ src = Wdt;   dst = dt_b; j = i - 32768; }
    else if (i < 1097728){ src = Wfc;   dst = fc_b; j = i - 49152; }
    else                 { src = Wproj; dst = pj_b; j = i - 1097728; }
    float4 v = ((const float4*)src)[j];
    u16x4 o = { f2b(v.x), f2b(v.y), f2b(v.z), f2b(v.w) };
    *(u16x4*)(dst + j*4) = o;
    return;
  }
  int row = bx - 8384;
  const float4* xr = (const float4*)(x + (size_t)row*1024);
  float4 v = xr[tid];
  float s1 = v.x+v.y+v.z+v.w;
  float s2 = v.x*v.x+v.y*v.y+v.z*v.z+v.w*v.w;
  #pragma unroll
  for (int m=1;m<64;m<<=1){ s1 += __shfl_xor(s1,m); s2 += __shfl_xor(s2,m); }
  int wv = tid>>6;
  if ((tid&63)==0){ red[wv]=s1; red[4+wv]=s2; }
  __syncthreads();
  s1 = red[0]+red[1]+red[2]+red[3];
  s2 = red[4]+red[5]+red[6]+red[7];
  float mu  = s1*(1.f/1024.f);
  float var = s2*(1.f/1024.f) - mu*mu;
  float rstd = rsqrtf(var + 1e-5f);
  float4 wv4 = ((const float4*)ln1w)[tid];
  float o0 = softplusf((v.x-mu)*rstd*wv4.x);
  float o1 = softplusf((v.y-mu)*rstd*wv4.y);
  float o2 = softplusf((v.z-mu)*rstd*wv4.z);
  float o3 = softplusf((v.w-mu)*rstd*wv4.w);
  u16x4 ob = { f2b(o0), f2b(o1), f2b(o2), f2b(o3) };
  *(u16x4*)(h0b + (size_t)row*1024 + tid*4) = ob;
}

// reduce 8 dbc split-K BF16 partials -> delta-GEMM bf16 input (cols 0..63) + f32 B/C (64..95)
__global__ void dbc_post(const u16* __restrict__ p, u16* __restrict__ delta_in,
                         float* __restrict__ BCf){
  int e = blockIdx.x*256 + threadIdx.x;          // 524288 = 4096*128
  int t = e >> 7, c = e & 127;
  float s = 0.f;
  #pragma unroll
  for (int z=0;z<8;z++) s += b2f(p[(size_t)z*524288 + e]);
  if (c < 64)      delta_in[t*64 + c] = f2b(s);
  else if (c < 96) BCf[t*32 + (c-64)] = s;
}

// out = p0+p1+p2+p3 + out  (proj split-K=4 reduce over BF16 partials; out holds h1)
// partials: 4 slices of 4M bf16 at z-stride 4194304 elements. 8 elems/thread, grid 2048.
__global__ void proj_reduce(const u16* __restrict__ p, float* __restrict__ out){
  int i = blockIdx.x*256 + threadIdx.x;          // over 512K groups of 8
  short8 a = ((const short8*)p)[i];
  short8 b = ((const short8*)(p + (size_t) 4194304))[i];
  short8 c = ((const short8*)(p + (size_t) 8388608))[i];
  short8 d = ((const short8*)(p + (size_t)12582912))[i];
  float4 r0 = ((const float4*)out)[i*2+0];
  float4 r1 = ((const float4*)out)[i*2+1];
  float s[8];
  #pragma unroll
  for (int k=0;k<8;k++)
    s[k] = b2f((u16)a[k]) + b2f((u16)b[k]) + b2f((u16)c[k]) + b2f((u16)d[k]);
  ((float4*)out)[i*2+0] = make_float4(s[0]+r0.x, s[1]+r0.y, s[2]+r0.z, s[3]+r0.w);
  ((float4*)out)[i*2+1] = make_float4(s[4]+r1.x, s[5]+r1.y, s[6]+r1.z, s[7]+r1.w);
}

__global__ __launch_bounds__(256)
void ln2_kernel(const float* __restrict__ x, const float* __restrict__ w,
                u16* __restrict__ outb)
{
  int row = blockIdx.x, tid = threadIdx.x;
  const float4* xr = (const float4*)(x + (size_t)row*1024);
  float4 v = xr[tid];
  float s1 = v.x+v.y+v.z+v.w;
  float s2 = v.x*v.x+v.y*v.y+v.z*v.z+v.w*v.w;
  #pragma unroll
  for (int m=1;m<64;m<<=1){ s1 += __shfl_xor(s1,m); s2 += __shfl_xor(s2,m); }
  __shared__ float red[8];
  int wv = tid>>6;
  if ((tid&63)==0){ red[wv]=s1; red[4+wv]=s2; }
  __syncthreads();
  s1 = red[0]+red[1]+red[2]+red[3];
  s2 = red[4]+red[5]+red[6]+red[7];
  float mu  = s1*(1.f/1024.f);
  float var = s2*(1.f/1024.f) - mu*mu;
  float rstd = rsqrtf(var + 1e-5f);
  float4 wv4 = ((const float4*)w)[tid];
  u16x4 ob = { f2b((v.x-mu)*rstd*wv4.x), f2b((v.y-mu)*rstd*wv4.y),
               f2b((v.z-mu)*rstd*wv4.z), f2b((v.w-mu)*rstd*wv4.w) };
  *(u16x4*)(outb + (size_t)row*1024 + tid*4) = ob;
}

// ---------------- MFMA GEMM (128x128, 2-barrier) — kept for the small GEMMs ----------------
// EPI 1: softplus(+bias) f32.  EPI 2: gelu bf16.  EPI 4: f32 split-K partial.
// EPI 5: BF16 split-K partial (outB at zstr*zb; zstr in u16 elements).
template<int EPI, int SWZ>
__global__ __launch_bounds__(256)
void gemm_bt(const u16* __restrict__ A, int lda,
             const u16* __restrict__ B, int ldb, int K,
             float* __restrict__ outF, u16* __restrict__ outB, int ldo,
             const float* __restrict__ bias, size_t zstr)
{
  __shared__ u16 sA[128*32];
  __shared__ u16 sB[128*32];
  const int tid = threadIdx.x;
  int m_blk, n_blk, zb;
  if (SWZ == 0){ n_blk = blockIdx.x; m_blk = blockIdx.y; zb = blockIdx.z; }
  else if (SWZ == 1){
    int b = blockIdx.x, xcd = b & 7, local = b >> 3;
    m_blk = (xcd>>2)*16 + (local & 15);
    n_blk = (xcd&3)*8 + (local >> 4);
    zb = 0;
  } else {
    int b = blockIdx.x, xcd = b & 7, local = b >> 3;
    m_blk = (xcd>>1)*8 + (local & 7);
    n_blk = local >> 3;
    zb = xcd & 1;
  }
  const int m0 = m_blk*128, n0 = n_blk*128;
  const int kstart = zb * K;
  const int wave = tid>>6, lane = tid&63;
  const int wm = (wave>>1)*64, wn = (wave&1)*64;
  const int lr = lane&15, quad = lane>>4;

  floatx4 acc[4][4];
  #pragma unroll
  for (int i=0;i<4;i++)
    #pragma unroll
    for (int j=0;j<4;j++){ floatx4 z = {0.f,0.f,0.f,0.f}; acc[i][j]=z; }

  const int r0 = tid>>2;
  const int kc8 = (((tid&3) ^ ((tid>>3)&3)))*8;   // swizzled source k-offset (u16 units)
  const int sswz = ((lr>>1)&3);                    // reader slot xor term
  for (int k0=kstart; k0<kstart+K; k0+=32){
    __syncthreads();
    async_copy16(A + (size_t)(m0+r0)*lda    + k0+kc8, &sA[(size_t)tid*8]);
    async_copy16(A + (size_t)(m0+64+r0)*lda + k0+kc8, &sA[(size_t)(tid+256)*8]);
    async_copy16(B + (size_t)(n0+r0)*ldb    + k0+kc8, &sB[(size_t)tid*8]);
    async_copy16(B + (size_t)(n0+64+r0)*ldb + k0+kc8, &sB[(size_t)(tid+256)*8]);
    __syncthreads();
    short8 af[4], bf[4];
    #pragma unroll
    for (int i=0;i<4;i++){
      af[i] = *(const short8*)&sA[(wm+i*16+lr)*32 + (quad^sswz)*8];
      bf[i] = *(const short8*)&sB[(wn+i*16+lr)*32 + (quad^sswz)*8];
    }
    #pragma unroll
    for (int i=0;i<4;i++)
      #pragma unroll
      for (int j=0;j<4;j++)
        acc[i][j] = __builtin_amdgcn_mfma_f32_16x16x32_bf16(af[i], bf[j], acc[i][j], 0,0,0);
  }
  #pragma unroll
  for (int i=0;i<4;i++){
    #pragma unroll
    for (int j=0;j<4;j++){
      #pragma unroll
      for (int r=0;r<4;r++){
        int gr = m0 + wm + i*16 + quad*4 + r;
        int gc = n0 + wn + j*16 + lr;
        float v = acc[i][j][r];
        size_t o = (size_t)gr*ldo + gc;
        if (EPI==1)      outF[o] = softplusf(v + bias[gc]);
        else if (EPI==2) outB[o] = f2b(geluf(v));
        else if (EPI==5) outB[zstr*zb + o] = f2b(v);
        else             outF[zstr*zb + o] = v;
      }
    }
  }
}

// ---------------- 256x256 pipelined GEMM: asm ds_read + frag read-ahead + counted vmcnt --
// (round-7 proven structure; 44us / MfmaUtil 31% on FC and proj at K=1024)
// EPI 2: gelu->bf16 store.  EPI 4: BF16 split-K partial store to outB at zstr*zb.
// Last-tile dummy stages target tile NT-1's addresses (L2-hot; r11: FETCH 26.3->24.8MB).
// NO atomics / NO intra-kernel cross-block reduction (r5/r6/r8 failures — see history).
// SWZ 3: FC 16x16 blocks, XCD supertile 8m x 4n.
// SWZ 4: proj — zb=xcd>>1, m=(xcd&1)*8+(local&7), n=local>>3.
template<int EPI, int SWZ>
__global__ __launch_bounds__(512, 2)
void gemm256(const u16* __restrict__ A, int lda,
             const u16* __restrict__ B, int ldb, int K,
             u16* __restrict__ outB, int ldo, size_t zstr)
{
  __shared__ u16 sA[2][4][4096];   // [buf][unit=ks*2+half][128*32]
  __shared__ u16 sB[2][4][4096];
  const int tid = threadIdx.x;
  int m_blk, n_blk, zb;
  if (SWZ == 3){
    int b = blockIdx.x, xcd = b & 7, local = b >> 3;
    m_blk = (xcd>>2)*8 + (local & 7);
    n_blk = (xcd&3)*4 + (local >> 3);
    zb = 0;
  } else {
    int b = blockIdx.x, xcd = b & 7, local = b >> 3;
    zb    = xcd >> 1;
    m_blk = (xcd&1)*8 + (local & 7);
    n_blk = local >> 3;
  }
  const int m0 = m_blk*256, n0 = n_blk*256;
  const int kstart = zb*K;
  const int wave = tid>>6, lane = tid&63;
  const int mq = wave>>2, nq = wave&3;
  const int lr = lane&15, quad = lane>>4;
  const int sswz = (lr>>1)&3;

  // staging source addressing (pre-swizzled chunk, rule 21: linear LDS dest)
  const int srow = tid>>2;
  const int scol = ((tid&3) ^ ((tid>>3)&3))*8;
  const u16* pa = A + (size_t)(m0 + srow)*lda + scol;
  const u16* pb = B + (size_t)(n0 + srow)*ldb + scol;
  u16* la = (u16*)sA + tid*8;
  u16* lb = (u16*)sB + tid*8;
  const size_t ah128 = (size_t)128*lda;
  const size_t bh128 = (size_t)128*ldb;

  // reader bases (u16 offsets inside one buffer)
  const int a_rd = (mq*64 + lr)*32 + (quad^sswz)*8;
  const int b_rd = ((nq&1)*64 + lr)*32 + (quad^sswz)*8;
  const int bun  = nq>>1;                       // B row-half this wave reads
  // asm ds_read byte-offset bases (unit byte off = BUF*32768 + KS*16384 + H*8192)
  const u32 a_rdB = ldsoff(sA) + (u32)(a_rd*2);
  const u32 b_rdB = ldsoff(sB) + (u32)(b_rd*2) + (u32)(bun*8192);

  floatx4 acc[2][4][4];
  #pragma unroll
  for (int h=0;h<2;h++)
    #pragma unroll
    for (int i=0;i<4;i++)
      #pragma unroll
      for (int j=0;j<4;j++){ floatx4 z={0.f,0.f,0.f,0.f}; acc[h][i][j]=z; }

  short8 af[2][4], bf[2][4];

#define STG_A(NB,KS,H,KT) async_copy16(pa + (size_t)(H)*ah128 + (size_t)((KT) + (KS)*32), \
                                       la + (NB)*16384 + ((KS)*2+(H))*4096)
#define STG_B(NB,KS,H,KT) async_copy16(pb + (size_t)(H)*bh128 + (size_t)((KT) + (KS)*32), \
                                       lb + (NB)*16384 + ((KS)*2+(H))*4096)

// MFS/MBS: frag sets consumed by this phase's MFMA; AH: acc row-half.
// PRBUF/PRKS/PRAH: unit for next phase's A pre-read (into af[MFS^1]);
// PRB: also pre-read B unit (PRKS,bun) into bf[MBS^1].
#define PH(MFS, MBS, AH, PRBUF, PRKS, PRAH, PRB, VM, LG, STMTS)               \
  {                                                                           \
    STMTS;                                                                    \
    asm volatile("s_waitcnt vmcnt(" VM ")" ::: "memory");                     \
    __builtin_amdgcn_s_barrier();                                             \
    ds_read128x4(a_rdB + (PRBUF)*32768u + (PRKS)*16384u + (PRAH)*8192u,       \
                 af[(MFS)^1]);                                                \
    if (PRB)                                                                  \
      ds_read128x4(b_rdB + (PRBUF)*32768u + (PRKS)*16384u, bf[(MBS)^1]);      \
    asm volatile("s_waitcnt lgkmcnt(" LG ")" ::: "memory");                   \
    __builtin_amdgcn_sched_barrier(0);                                        \
    __builtin_amdgcn_s_setprio(1);                                            \
    _Pragma("unroll")                                                         \
    for (int i_=0;i_<4;i_++)                                                  \
      _Pragma("unroll")                                                       \
      for (int j_=0;j_<4;j_++)                                                \
        acc[AH][i_][j_] = __builtin_amdgcn_mfma_f32_16x16x32_bf16(            \
            af[MFS][i_], bf[MBS][j_], acc[AH][i_][j_], 0,0,0);                \
    __builtin_amdgcn_s_setprio(0);                                            \
  }

  // prologue: stage tile 0 (FIFO unit order) into buf0; confirm u0-u2; pre-read ph0 frags
  STG_A(0,0,0,kstart); STG_B(0,0,0,kstart);
  STG_B(0,0,1,kstart); STG_A(0,0,1,kstart);
  STG_B(0,1,0,kstart); STG_B(0,1,1,kstart);
  STG_A(0,1,0,kstart); STG_A(0,1,1,kstart);
  asm volatile("s_waitcnt vmcnt(5)" ::: "memory");
  __builtin_amdgcn_s_barrier();
  ds_read128x4(a_rdB, af[0]);       // buf0, unit A(ks0,h0)
  ds_read128x4(b_rdB, bf[0]);       // buf0, unit B(ks0,bun)

  const int NT = K >> 6;                          // 16 for both GEMMs (even)
  for (int t=0; t<NT; t+=2){
    const int ka = kstart + (t+1)*64;                         // stage tile t+1
    const int kb = (t+2 < NT) ? (kstart + (t+2)*64) : ka;     // t+2, or L2-HOT dummy (=ka)
    // tile t in buf0, staging t+1 -> buf1
    PH(0,0,0, 0,0,1,0, "6","4", STG_A(1,0,0,ka); STG_B(1,0,0,ka));
    PH(1,0,1, 0,1,0,1, "5","8", STG_B(1,0,1,ka); STG_A(1,0,1,ka));
    PH(0,1,0, 0,1,1,0, "6","4", STG_B(1,1,0,ka); STG_B(1,1,1,ka));
    PH(1,1,1, 1,0,0,1, "5","8", STG_A(1,1,0,ka); STG_A(1,1,1,ka));
    // tile t+1 in buf1, staging t+2 -> buf0
    PH(0,0,0, 1,0,1,0, "6","4", STG_A(0,0,0,kb); STG_B(0,0,0,kb));
    PH(1,0,1, 1,1,0,1, "5","8", STG_B(0,0,1,kb); STG_A(0,0,1,kb));
    PH(0,1,0, 1,1,1,0, "6","4", STG_B(0,1,0,kb); STG_B(0,1,1,kb));
    PH(1,1,1, 0,0,0,1, "5","8", STG_A(0,1,0,kb); STG_A(0,1,1,kb));
  }

#undef PH
#undef STG_A
#undef STG_B

  #pragma unroll
  for (int h=0;h<2;h++){
    #pragma unroll
    for (int i=0;i<4;i++){
      #pragma unroll
      for (int j=0;j<4;j++){
        #pragma unroll
        for (int r=0;r<4;r++){
          int gr = m0 + h*128 + mq*64 + i*16 + quad*4 + r;
          int gc = n0 + nq*64 + j*16 + lr;
          float v = acc[h][i][j][r];
          size_t o = (size_t)gr*ldo + gc;
          if (EPI==2) outB[o] = f2b(geluf(v));
          else        outB[zstr*zb + o] = f2b(v);   // EPI==4 bf16 split-K partial
        }
      }
    }
  }
}

// ---------------- chunked selective scan (32 chunks x 32 steps) ----------------
// chains: (b, d) = 4096. Lane owns (b, d, chunk), 16 n-states in registers.
// x (=h0) is read as BF16 from h0b — consistent with the dbc GEMM that produced delta.
// blk bits: [0:2)=d-block(4), [2:7)=chunk(32), [7:9)=b(4) -> grid 512
__global__ __launch_bounds__(256)
void scan_p1(const float* __restrict__ delta, const u16* __restrict__ h0b,
             const float* __restrict__ BCf, const float* __restrict__ A_log,
             float* __restrict__ Pbuf, float* __restrict__ Sbuf)
{
  int blk = blockIdx.x;
  int d = (blk & 3)*256 + threadIdx.x;
  int c = (blk >> 2) & 31;
  int b = blk >> 7;
  float a2[16], h[16], P[16];
  #pragma unroll
  for (int n=0;n<16;n++){ a2[n] = -__expf(A_log[d*16+n]) * 1.44269504f; h[n]=0.f; P[n]=1.f; }
  int t0 = c*32;
  const float* dptr = delta + ((size_t)(b*1024 + t0))*1024 + d;
  const u16*   xptr = h0b   + ((size_t)(b*1024 + t0))*1024 + d;
  const float* bc   = BCf   + ((size_t)(b*1024 + t0))*32;
  #pragma unroll 4
  for (int t=0;t<32;t++){
    float dlt = dptr[t*1024];
    float xv  = b2f(xptr[t*1024]);
    float dx = dlt*xv;
    #pragma unroll
    for (int n=0;n<16;n++){
      float dA = exp2f(dlt*a2[n]);
      h[n] = dA*h[n] + dx*bc[t*32+n];
      P[n] *= dA;
    }
  }
  size_t base = ((size_t)((b*32 + c)*16))*1024 + d;
  #pragma unroll
  for (int n=0;n<16;n++){ Pbuf[base + (size_t)n*1024] = P[n]; Sbuf[base + (size_t)n*1024] = h[n]; }
}

// blk bits: [0:2)=d-block(4), [2:6)=n(16), [6:8)=b(4) -> grid 256
// dependent-chain software pipeline: chunk c+1's P/S loads issue before chunk c's
// H-update, hiding one HBM latency per iteration (1 block/CU, latency-bound kernel).
__global__ __launch_bounds__(256)
void scan_p2(const float* __restrict__ Pbuf, const float* __restrict__ Sbuf,
             float* __restrict__ Hbuf)
{
  int blk = blockIdx.x;
  int d = (blk & 3)*256 + threadIdx.x;
  int n = (blk >> 2) & 15;
  int b = blk >> 6;
  const size_t cstr = (size_t)16*1024;
  size_t idx = ((size_t)((b*32 + 0)*16 + n))*1024 + d;
  float H = 0.f;
  float P = Pbuf[idx], S = Sbuf[idx];
  for (int c=0;c<32;c++){
    float Pn = 0.f, Sn = 0.f;
    if (c < 31){ Pn = Pbuf[idx + cstr]; Sn = Sbuf[idx + cstr]; }
    Hbuf[idx] = H;
    H = P*H + S;
    P = Pn; S = Sn;
    idx += cstr;
  }
}

// writes h1 directly into `out` (residual base; ln2 + proj_reduce read it there)
__global__ __launch_bounds__(256)
void scan_p3(const float* __restrict__ delta, const u16* __restrict__ h0b,
             const float* __restrict__ BCf, const float* __restrict__ A_log,
             const float* __restrict__ Hbuf, const float* __restrict__ Dp,
             float* __restrict__ outp)
{
  int blk = blockIdx.x;
  int d = (blk & 3)*256 + threadIdx.x;
  int c = (blk >> 2) & 31;
  int b = blk >> 7;
  float a2[16], h[16];
  size_t hb = ((size_t)((b*32 + c)*16))*1024 + d;
  #pragma unroll
  for (int n=0;n<16;n++){
    a2[n] = -__expf(A_log[d*16+n]) * 1.44269504f;
    h[n] = Hbuf[hb + (size_t)n*1024];
  }
  float dpv = 1.f + Dp[d];
  int t0 = c*32;
  const float* dptr = delta + ((size_t)(b*1024 + t0))*1024 + d;
  const u16*   xptr = h0b   + ((size_t)(b*1024 + t0))*1024 + d;
  const float* bc   = BCf   + ((size_t)(b*1024 + t0))*32;
  float* wptr = outp + ((size_t)(b*1024 + t0))*1024 + d;
  #pragma unroll 4
  for (int t=0;t<32;t++){
    float dlt = dptr[t*1024];
    float xv  = b2f(xptr[t*1024]);
    float dx = dlt*xv;
    float y = 0.f;
    #pragma unroll
    for (int n=0;n<16;n++){
      float dA = exp2f(dlt*a2[n]);
      h[n] = dA*h[n] + dx*bc[t*32+n];
      y += h[n]*bc[t*32+16+n];
    }
    wptr[t*1024] = xv*dpv + y;
  }
}

// ---------------- launch ----------------
extern "C" void kernel_launch(void* const* d_in, const int* in_sizes, int n_in,
                              void* d_out, int out_size, void* d_ws, size_t ws_size,
                              hipStream_t stream)
{
  const float* x    = (const float*)d_in[0];
  const float* ln1w = (const float*)d_in[1];
  const float* ln2w = (const float*)d_in[2];
  const float* Wdbc = (const float*)d_in[3];
  const float* Wdt  = (const float*)d_in[4];
  const float* bdt  = (const float*)d_in[5];
  const float* Alog = (const float*)d_in[6];
  const float* Dp   = (const float*)d_in[7];
  const float* Wfc  = (const float*)d_in[8];
  const float* Wproj= (const float*)d_in[9];
  float* out = (float*)d_out;

  char* ws = (char*)d_ws;
  size_t off = 0;
  auto carve = [&](size_t bytes)->char*{ char* p = ws + off; off += (bytes + 255) & ~(size_t)255; return p; };
  const size_t T = 4096;                       // B*L tokens
  float* dlt   = (float*)carve(T*1024*4);
  float* Pbuf  = (float*)carve((size_t)4*32*16*1024*4);   // 8MB
  float* Sbuf  = (float*)carve((size_t)4*32*16*1024*4);   // 8MB
  float* Hbuf  = (float*)carve((size_t)4*32*16*1024*4);   // 8MB
  float* pad_  = (float*)carve((size_t)4*32*16*1024*4);   // 8MB (alias space)
  float* BCf   = (float*)carve(T*32*4);
  u16*   h0b   = (u16*)  carve(T*1024*2);
  u16*   m0b   = (u16*)  carve(T*1024*2);
  u16*   g_b   = (u16*)  carve(T*4096*2);
  u16*   din_b = (u16*)  carve(T*64*2);
  u16*   Wdbc_b= (u16*)  carve((size_t)128*1024*2);
  u16*   Wdt_b = (u16*)  carve((size_t)1024*64*2);
  u16*   Wfc_b = (u16*)  carve((size_t)4096*1024*2);
  u16*   Wpj_b = (u16*)  carve((size_t)1024*4096*2);
  // lifetime-disjoint aliases:
  // dbc BF16 partials: 8 x 4096x128 x 2B = 8MiB alias on Hbuf (dead before scan_p2).
  u16* dbc_pb = (u16*)Hbuf;
  // proj split-K=4 BF16 partials: 4 x 4M x 2B = 32MiB over [dlt, Pbuf, Sbuf] (exactly
  // 32MiB contiguous; all dead after scan_p3).
  u16* proj_p = (u16*)dlt;
  (void)pad_; (void)ws_size; (void)in_sizes; (void)n_in; (void)out_size;

  // fused head: weight casts + LN1 (bf16-only output)
  prep_ln1<<<12480, 256, 0, stream>>>(Wdbc, Wdt, Wfc, Wproj,
                                      Wdbc_b, Wdt_b, Wfc_b, Wpj_b,
                                      x, ln1w, h0b);

  // dbc = h0 @ W_dbc^T  (N padded to 128), split-K=8 BF16 partials
  gemm_bt<5,0><<<dim3(1,32,8), 256, 0, stream>>>(h0b, 1024, Wdbc_b, 1024, 128,
                                                 nullptr, dbc_pb, 128, nullptr, (size_t)T*128);
  // reduce bf16 partials -> delta-input bf16 + B/C f32
  dbc_post<<<2048, 256, 0, stream>>>(dbc_pb, din_b, BCf);

  // delta = softplus(din @ W_dt^T + b_dt), f32 out
  gemm_bt<1,0><<<dim3(8,32), 256, 0, stream>>>(din_b, 64, Wdt_b, 64, 64,
                                               dlt, nullptr, 1024, bdt, 0);

  // selective scan -> out = h1 = h0*(1+Dp) + y  (residual base; ln2 reads it)
  scan_p1<<<512, 256, 0, stream>>>(dlt, h0b, BCf, Alog, Pbuf, Sbuf);
  scan_p2<<<256, 256, 0, stream>>>(Pbuf, Sbuf, Hbuf);
  scan_p3<<<512, 256, 0, stream>>>(dlt, h0b, BCf, Alog, Hbuf, Dp, out);

  // m0 = LN2(h1) (bf16) — reads h1 from out
  ln2_kernel<<<4096, 256, 0, stream>>>(out, ln2w, m0b);

  // g = gelu(m0 @ W_fc^T) (bf16) — 256^2 pipelined (asm ds_read), XCD supertiled
  gemm256<2,3><<<256, 512, 0, stream>>>(m0b, 1024, Wfc_b, 1024, 1024,
                                        g_b, 4096, 0);

  // proj partials: g @ W_proj^T, split-K=4 BF16 partials
  gemm256<4,4><<<256, 512, 0, stream>>>(g_b, 4096, Wpj_b, 4096, 1024,
                                        proj_p, 1024, (size_t)T*1024);
  // out = p0+p1+p2+p3 + out (residual already in out)
  proj_reduce<<<2048, 256, 0, stream>>>(proj_p, out);
}